// Round 10
// baseline (688.663 us; speedup 1.0000x reference)
//
#include <hip/hip_runtime.h>

// SegDecoder: 3-layer cross-attention decoder on MI355X (gfx950).
// B=16, Nq=64, Nk=4096, C=512, H=8, hd=64, FF=2048, L=3.
// R10: big-GEMM gets the 8-phase fine interleave (4 phases/K-tile: per-phase
// {2 staging issues, A-quadrant ds_read, s_barrier, setprio, 16 MFMA,
// setprio, s_barrier}; B-frags register-resident per K-tile; __syncthreads
// only at K-tile boundary). Attention stays R9-flash (proven -107us).

typedef unsigned short u16;
typedef __attribute__((ext_vector_type(8))) short short8;
typedef __attribute__((ext_vector_type(4))) short short4v;
typedef __attribute__((ext_vector_type(4))) float f32x4;

__device__ __forceinline__ float b2f(u16 u) {
    union { unsigned int i; float f; } v; v.i = ((unsigned int)u) << 16; return v.f;
}
__device__ __forceinline__ u16 f2b(float f) {  // round-to-nearest-even
    unsigned int x = __float_as_uint(f);
    x += 0x7fffu + ((x >> 16) & 1u);
    return (u16)(x >> 16);
}

__device__ __forceinline__ float waveSum(float v) {
#pragma unroll
    for (int o = 32; o > 0; o >>= 1) v += __shfl_xor(v, o);
    return v;
}

// async global->LDS, 16B per lane. LDS dest is wave-uniform base + lane*16.
__device__ __forceinline__ void gl_lds16(const void* g, void* l) {
    __builtin_amdgcn_global_load_lds(
        (__attribute__((address_space(1))) void*)g,
        (__attribute__((address_space(3))) void*)l, 16, 0, 0);
}

// ---------------------------------------------------------------------------
// Big-GEMM (Kproj / VT): 256x256 tile, BK=64, 8 waves (2M x 4N), per-wave
// C = 128x64 (8x4 frags). 2-slot LDS (128KB). 4 phases per K-tile:
//   phase p: issue 2 staging rounds (kt+1) -> ds_read A-quadrant frags
//            (B frags read once at p=0, live in regs) -> s_barrier ->
//            setprio(1) -> 16 MFMA (quadrant p x full K=64) -> setprio(0)
//            -> s_barrier.
// K-tile boundary: __syncthreads (vmcnt(0)+lgkmcnt(0)+barrier) guards the
// slot swap. XCD-chunk block swizzle (bijective, R8-proven).
// ---------------------------------------------------------------------------
template<bool BIAS_ROW, bool HAS_BIAS, bool AFFC>
__global__ __launch_bounds__(512, 1) void gemm256x256_k(
    const u16* __restrict__ A, const u16* __restrict__ Bt,
    const float* __restrict__ bias, u16* __restrict__ Cout,
    int lda, int ldb, int ldc, long sA2, long sB2, long sC2,
    const float* __restrict__ affc)
{
    __shared__ u16 As[2][256][64];
    __shared__ u16 Bs[2][256][64];
    const int t = threadIdx.x;
    const int lane = t & 63;
    const int wave = t >> 6;

    const int gx = gridDim.x, gy = gridDim.y;
    const int nwg = gx * gy * gridDim.z;
    int id;
    {
        const int orig = blockIdx.x + blockIdx.y * gx + blockIdx.z * gx * gy;
        const int qq = nwg >> 3, rr = nwg & 7;
        const int xcd = orig & 7, sub = orig >> 3;
        id = (xcd < rr ? xcd * (qq + 1) : rr * (qq + 1) + (xcd - rr) * qq) + sub;
    }
    const int bx = id % gx;
    const int by = (id / gx) % gy;
    const int z  = id / (gx * gy);

    A  += (long)z * sA2;
    Bt += (long)z * sB2;
    const long cbase = (long)z * sC2;
    const int n0 = bx * 256;
    const int m0 = by * 256;
    const int wm = wave >> 2;         // 0..1
    const int wn = wave & 3;          // 0..3
    const int rl = lane & 15, uq = lane >> 4;
    const int srow = lane >> 3;
    const int up   = lane & 7;

    f32x4 acc[8][4];
#pragma unroll
    for (int i = 0; i < 8; ++i)
#pragma unroll
        for (int j = 0; j < 4; ++j) acc[i][j] = (f32x4){0.f, 0.f, 0.f, 0.f};

    // 8 staging rounds per K-tile: 0-3 = A rows rnd*64.., 4-7 = B rows.
    auto stage_round = [&](int buf, int kt, int rnd) {
        const int k0 = kt * 64;
        if (rnd < 4) {
            const int row = rnd * 64 + wave * 8 + srow;
            const int ul = up ^ (row & 7);
            gl_lds16(A + (long)(m0 + row) * lda + k0 + ul * 8,
                     &As[buf][rnd * 64 + wave * 8][0]);
        } else {
            const int r = rnd - 4;
            const int row = r * 64 + wave * 8 + srow;
            const int ul = up ^ (row & 7);
            gl_lds16(Bt + (long)(n0 + row) * ldb + k0 + ul * 8,
                     &Bs[buf][r * 64 + wave * 8][0]);
        }
    };

    // prologue: stage K-tile 0 fully, drain
#pragma unroll
    for (int rnd = 0; rnd < 8; ++rnd) stage_round(0, 0, rnd);
    __syncthreads();

    int buf = 0;
    for (int kt = 0; kt < 8; ++kt) {
        const int nbuf = buf ^ 1;
        short8 bf[2][4];
#pragma unroll
        for (int p = 0; p < 4; ++p) {
            if (kt < 7) {
                stage_round(nbuf, kt + 1, p * 2);
                stage_round(nbuf, kt + 1, p * 2 + 1);
            }
            if (p == 0) {
#pragma unroll
                for (int kc = 0; kc < 2; ++kc)
#pragma unroll
                    for (int j = 0; j < 4; ++j) {
                        const int Rb = wn * 64 + j * 16 + rl;
                        bf[kc][j] = *(const short8*)(
                            &Bs[buf][Rb][((kc * 4 + uq) ^ (Rb & 7)) * 8]);
                    }
            }
            short8 af[2][2];
#pragma unroll
            for (int kc = 0; kc < 2; ++kc)
#pragma unroll
                for (int i2 = 0; i2 < 2; ++i2) {
                    const int Ra = wm * 128 + (p * 2 + i2) * 16 + rl;
                    af[kc][i2] = *(const short8*)(
                        &As[buf][Ra][((kc * 4 + uq) ^ (Ra & 7)) * 8]);
                }
            __builtin_amdgcn_s_barrier();
            __builtin_amdgcn_s_setprio(1);
#pragma unroll
            for (int kc = 0; kc < 2; ++kc)
#pragma unroll
                for (int i2 = 0; i2 < 2; ++i2)
#pragma unroll
                    for (int j = 0; j < 4; ++j)
                        acc[p * 2 + i2][j] = __builtin_amdgcn_mfma_f32_16x16x32_bf16(
                            af[kc][i2], bf[kc][j], acc[p * 2 + i2][j], 0, 0, 0);
            __builtin_amdgcn_s_setprio(0);
            if (p < 3) __builtin_amdgcn_s_barrier();
        }
        __syncthreads();   // vmcnt(0): kt+1 staged; slot swap safe
        buf = nbuf;
    }

    const int r0 = (lane >> 4) * 4;
    const int c0 = lane & 15;
#pragma unroll
    for (int i = 0; i < 8; ++i) {
#pragma unroll
        for (int j = 0; j < 4; ++j) {
#pragma unroll
            for (int r = 0; r < 4; ++r) {
                const int row = m0 + wm * 128 + i * 16 + r0 + r;
                const int col = n0 + wn * 64 + j * 16 + c0;
                float v = acc[i][j][r];
                if constexpr (HAS_BIAS) {
                    if constexpr (BIAS_ROW) v += bias[row]; else v += bias[col];
                }
                if constexpr (AFFC) v *= affc[(long)z * 4096 + col];
                Cout[cbase + (long)row * ldc + col] = f2b(v);
            }
        }
    }
}

// ---------------------------------------------------------------------------
// Flash attention partial (R9, proven): block = (split, bh).
// ---------------------------------------------------------------------------
__global__ __launch_bounds__(256) void fattn_k(
    const u16* __restrict__ q16, const u16* __restrict__ K16,
    const u16* __restrict__ VT16, float* __restrict__ Op,
    float2* __restrict__ ml)
{
    __shared__ u16 Qs[64][64];
    __shared__ u16 Ks[128][64];
    __shared__ u16 Vs[64][128];
    __shared__ u16 Ps[64][128];
    const int t = threadIdx.x;
    const int lane = t & 63;
    const int w = t >> 6;
    const int bh = blockIdx.y;
    const int split = blockIdx.x;
    const int b = bh >> 3, h = bh & 7;
    const int kbase = split * 1024;
    const int rl = lane & 15, uq = lane >> 4;
    const int r0 = (lane >> 4) * 4;
    const int c0 = lane & 15;
    const int srow8 = lane >> 3, up8 = lane & 7;
    const int srow4 = lane >> 4, up16 = lane & 15;

#pragma unroll
    for (int rnd = 0; rnd < 2; ++rnd) {
        const int row = rnd * 32 + w * 8 + srow8;
        const int ul = up8 ^ (row & 7);
        gl_lds16(q16 + ((long)(b * 64 + row)) * 512 + h * 64 + ul * 8,
                 &Qs[rnd * 32 + w * 8][0]);
    }

    f32x4 O[4];
#pragma unroll
    for (int n = 0; n < 4; ++n) O[n] = (f32x4){0.f, 0.f, 0.f, 0.f};
    float m_run[4] = {-3.0e38f, -3.0e38f, -3.0e38f, -3.0e38f};
    float l_run[4] = {0.f, 0.f, 0.f, 0.f};

    const int R = w * 16 + rl;

    for (int tt = 0; tt < 8; ++tt) {
        __syncthreads();
#pragma unroll
        for (int rnd = 0; rnd < 4; ++rnd) {
            const int row = rnd * 32 + w * 8 + srow8;
            const int ul = up8 ^ (row & 7);
            gl_lds16(K16 + ((long)(b * 4096 + kbase + tt * 128 + row)) * 512
                         + h * 64 + ul * 8,
                     &Ks[rnd * 32 + w * 8][0]);
        }
#pragma unroll
        for (int rnd = 0; rnd < 4; ++rnd) {
            const int row = rnd * 16 + w * 4 + srow4;
            const int ul = up16 ^ (row & 15);
            gl_lds16(VT16 + (long)b * 2097152 + ((long)(h * 64 + row)) * 4096
                         + kbase + tt * 128 + ul * 8,
                     &Vs[rnd * 16 + w * 4][0]);
        }
        __syncthreads();

        f32x4 s[8];
        short8 af[2];
#pragma unroll
        for (int kc = 0; kc < 2; ++kc)
            af[kc] = *(const short8*)(&Qs[R][((kc * 4 + uq) ^ (R & 7)) * 8]);
#pragma unroll
        for (int j = 0; j < 8; ++j) {
            s[j] = (f32x4){0.f, 0.f, 0.f, 0.f};
            const int Rb = j * 16 + rl;
#pragma unroll
            for (int kc = 0; kc < 2; ++kc) {
                short8 bf = *(const short8*)(&Ks[Rb][((kc * 4 + uq) ^ (Rb & 7)) * 8]);
                s[j] = __builtin_amdgcn_mfma_f32_16x16x32_bf16(af[kc], bf, s[j], 0, 0, 0);
            }
        }
#pragma unroll
        for (int j = 0; j < 8; ++j)
#pragma unroll
            for (int r = 0; r < 4; ++r) s[j][r] *= 0.125f;

        float mv[4];
#pragma unroll
        for (int r = 0; r < 4; ++r) {
            float m = s[0][r];
#pragma unroll
            for (int j = 1; j < 8; ++j) m = fmaxf(m, s[j][r]);
#pragma unroll
            for (int mask = 1; mask < 16; mask <<= 1)
                m = fmaxf(m, __shfl_xor(m, mask));
            mv[r] = m;
        }
        float al[4], rs[4];
#pragma unroll
        for (int r = 0; r < 4; ++r) {
            const float mn = fmaxf(m_run[r], mv[r]);
            al[r] = __expf(m_run[r] - mn);
            m_run[r] = mn;
            rs[r] = 0.f;
        }
#pragma unroll
        for (int j = 0; j < 8; ++j)
#pragma unroll
            for (int r = 0; r < 4; ++r) {
                s[j][r] = __expf(s[j][r] - m_run[r]);
                rs[r] += s[j][r];
            }
#pragma unroll
        for (int r = 0; r < 4; ++r) {
#pragma unroll
            for (int mask = 1; mask < 16; mask <<= 1)
                rs[r] += __shfl_xor(rs[r], mask);
            l_run[r] = l_run[r] * al[r] + rs[r];
        }
#pragma unroll
        for (int n = 0; n < 4; ++n)
#pragma unroll
            for (int r = 0; r < 4; ++r) O[n][r] *= al[r];

#pragma unroll
        for (int j = 0; j < 8; ++j)
#pragma unroll
            for (int r = 0; r < 4; ++r) {
                const int row = w * 16 + r0 + r;
                const int col = j * 16 + c0;
                Ps[row][(((col >> 3) ^ (row & 15)) << 3) + (col & 7)] = f2b(s[j][r]);
            }
#pragma unroll
        for (int kc4 = 0; kc4 < 4; ++kc4) {
            const short8 afp = *(const short8*)(&Ps[R][(((kc4 * 4 + uq) ^ (R & 15)) << 3)]);
#pragma unroll
            for (int n = 0; n < 4; ++n) {
                const int Rv = n * 16 + rl;
                const short8 bfv = *(const short8*)(&Vs[Rv][(((kc4 * 4 + uq) ^ (Rv & 15)) << 3)]);
                O[n] = __builtin_amdgcn_mfma_f32_16x16x32_bf16(afp, bfv, O[n], 0, 0, 0);
            }
        }
    }

    const long obase = ((long)(split * 128 + bh)) * 64;
#pragma unroll
    for (int n = 0; n < 4; ++n)
#pragma unroll
        for (int r = 0; r < 4; ++r) {
            const int q = w * 16 + r0 + r;
            Op[(obase + q) * 64 + n * 16 + c0] = O[n][r];
        }
    if (c0 == 0) {
#pragma unroll
        for (int r = 0; r < 4; ++r) {
            const int q = w * 16 + r0 + r;
            ml[obase + q] = make_float2(m_run[r], l_run[r]);
        }
    }
}

// merge 4 flash splits -> o16 (B,Nq,C)
__global__ __launch_bounds__(256) void fmerge_k(
    const float* __restrict__ Op, const float2* __restrict__ ml,
    u16* __restrict__ o16)
{
    const int i = blockIdx.x * 256 + threadIdx.x;
    const int d4 = i & 15;
    const int q  = (i >> 4) & 63;
    const int bh = i >> 10;
    const float2 m0 = ml[((long)(0 * 128 + bh)) * 64 + q];
    const float2 m1 = ml[((long)(1 * 128 + bh)) * 64 + q];
    const float2 m2 = ml[((long)(2 * 128 + bh)) * 64 + q];
    const float2 m3 = ml[((long)(3 * 128 + bh)) * 64 + q];
    const float m = fmaxf(fmaxf(m0.x, m1.x), fmaxf(m2.x, m3.x));
    const float e0 = __expf(m0.x - m), e1 = __expf(m1.x - m);
    const float e2 = __expf(m2.x - m), e3 = __expf(m3.x - m);
    const float inv = 1.f / (m0.y * e0 + m1.y * e1 + m2.y * e2 + m3.y * e3);
    const float4 v0 = *(const float4*)(Op + (((long)(0 * 128 + bh)) * 64 + q) * 64 + d4 * 4);
    const float4 v1 = *(const float4*)(Op + (((long)(1 * 128 + bh)) * 64 + q) * 64 + d4 * 4);
    const float4 v2 = *(const float4*)(Op + (((long)(2 * 128 + bh)) * 64 + q) * 64 + d4 * 4);
    const float4 v3 = *(const float4*)(Op + (((long)(3 * 128 + bh)) * 64 + q) * 64 + d4 * 4);
    float4 acc;
    acc.x = (v0.x * e0 + v1.x * e1 + v2.x * e2 + v3.x * e3) * inv;
    acc.y = (v0.y * e0 + v1.y * e1 + v2.y * e2 + v3.y * e3) * inv;
    acc.z = (v0.z * e0 + v1.z * e1 + v2.z * e2 + v3.z * e3) * inv;
    acc.w = (v0.w * e0 + v1.w * e1 + v2.w * e2 + v3.w * e3) * inv;
    const int b = bh >> 3, h = bh & 7;
    short4v r;
    r[0] = (short)f2b(acc.x); r[1] = (short)f2b(acc.y);
    r[2] = (short)f2b(acc.z); r[3] = (short)f2b(acc.w);
    *(short4v*)(o16 + (long)b * 32768 + q * 512 + h * 64 + d4 * 4) = r;
}

// ---------------------------------------------------------------------------
// Generic batched GEMM: C = alpha*A@Bt^T [+bias][relu]; BK=64 single-buffered.
// ---------------------------------------------------------------------------
template<int TM, int TN, bool OUT_BF16, bool RELU, bool BIAS_ROW, bool HAS_BIAS>
__global__ __launch_bounds__(256) void gemm_bt_k(
    const u16* __restrict__ A, const u16* __restrict__ Bt,
    const float* __restrict__ bias, void* __restrict__ Cout,
    int K, int lda, int ldb, int ldc,
    long sA1, long sB1, long sC1, float alpha)
{
    __shared__ u16 As[TM][64];
    __shared__ u16 Bs[TN][64];
    const int t = threadIdx.x;
    const int lane = t & 63;
    const int wave = t >> 6;
    const int z = blockIdx.z;
    A  += (long)z * sA1;
    Bt += (long)z * sB1;
    const long cbase = (long)z * sC1;
    const int n0 = blockIdx.x * TN;
    const int m0 = blockIdx.y * TM;
    constexpr int FM = TM / 32, FN = TN / 32;
    const int wr = wave >> 1, wc = wave & 1;
    const int rl = lane & 15, uq = lane >> 4;

    f32x4 acc[FM][FN];
#pragma unroll
    for (int i = 0; i < FM; ++i)
#pragma unroll
        for (int j = 0; j < FN; ++j) acc[i][j] = (f32x4){0.f, 0.f, 0.f, 0.f};

    const int srow = lane >> 3;
    const int up   = lane & 7;

    for (int k0 = 0; k0 < K; k0 += 64) {
        __syncthreads();
#pragma unroll
        for (int r = 0; r < TM / 32; ++r) {
            const int br = (wave * (TM / 32) + r) * 8;
            const int row = br + srow;
            const int ul = up ^ (row & 7);
            gl_lds16(A + (long)(m0 + row) * lda + k0 + ul * 8, &As[br][0]);
        }
#pragma unroll
        for (int r = 0; r < TN / 32; ++r) {
            const int br = (wave * (TN / 32) + r) * 8;
            const int row = br + srow;
            const int ul = up ^ (row & 7);
            gl_lds16(Bt + (long)(n0 + row) * ldb + k0 + ul * 8, &Bs[br][0]);
        }
        __syncthreads();

#pragma unroll
        for (int kc = 0; kc < 2; ++kc) {
            short8 af[FM], bf[FN];
#pragma unroll
            for (int i = 0; i < FM; ++i) {
                const int R = wr * (TM / 2) + i * 16 + rl;
                af[i] = *(const short8*)(&As[R][((kc * 4 + uq) ^ (R & 7)) * 8]);
            }
#pragma unroll
            for (int j = 0; j < FN; ++j) {
                const int R = wc * (TN / 2) + j * 16 + rl;
                bf[j] = *(const short8*)(&Bs[R][((kc * 4 + uq) ^ (R & 7)) * 8]);
            }
#pragma unroll
            for (int i = 0; i < FM; ++i)
#pragma unroll
                for (int j = 0; j < FN; ++j)
                    acc[i][j] = __builtin_amdgcn_mfma_f32_16x16x32_bf16(
                        af[i], bf[j], acc[i][j], 0, 0, 0);
        }
    }

    const int r0 = (lane >> 4) * 4;
    const int c0 = lane & 15;
#pragma unroll
    for (int i = 0; i < FM; ++i) {
#pragma unroll
        for (int j = 0; j < FN; ++j) {
#pragma unroll
            for (int r = 0; r < 4; ++r) {
                const int row = m0 + wr * (TM / 2) + i * 16 + r0 + r;
                const int col = n0 + wc * (TN / 2) + j * 16 + c0;
                float v = acc[i][j][r] * alpha;
                if constexpr (HAS_BIAS) {
                    if constexpr (BIAS_ROW) v += bias[row]; else v += bias[col];
                }
                if constexpr (RELU) v = fmaxf(v, 0.f);
                const long idx = cbase + (long)row * ldc + col;
                if constexpr (OUT_BF16) ((u16*)Cout)[idx] = f2b(v);
                else                    ((float*)Cout)[idx] = v;
            }
        }
    }
}

// split-K FF2 reduce + bias
__global__ __launch_bounds__(256) void ffred_k(
    const float* __restrict__ part, const float* __restrict__ bias,
    float* __restrict__ out)
{
    const int i = (blockIdx.x * 256 + threadIdx.x) * 4;
    const int c = i & 511;
    float4 s = *(const float4*)(part + i);
#pragma unroll
    for (int sp = 1; sp < 4; ++sp) {
        const float4 v = *(const float4*)(part + (long)sp * 524288 + i);
        s.x += v.x; s.y += v.y; s.z += v.z; s.w += v.w;
    }
    s.x += bias[c]; s.y += bias[c + 1]; s.z += bias[c + 2]; s.w += bias[c + 3];
    *(float4*)(out + i) = s;
}

// u[l][b][c'] = sum_c Wk[l][c'][c] * extra[b][c]
__global__ __launch_bounds__(256) void umat_k(
    const float* __restrict__ Wk, const float* __restrict__ extra,
    float* __restrict__ u)
{
    __shared__ float ex[16][512];
    const int l = blockIdx.x;
    const int t = threadIdx.x;
    for (int i = t; i < 16 * 512 / 4; i += 256)
        ((float4*)&ex[0][0])[i] = ((const float4*)extra)[i];
    __syncthreads();
    const int lane = t & 63, wave = t >> 6;
    const int row = blockIdx.y * 4 + wave;
    const float* wrow = Wk + ((size_t)l * 512 + row) * 512 + lane * 8;
    float w[8];
#pragma unroll
    for (int j = 0; j < 8; ++j) w[j] = wrow[j];
    float s[16];
#pragma unroll
    for (int b = 0; b < 16; ++b) {
        float x = 0.f;
#pragma unroll
        for (int j = 0; j < 8; ++j) x += w[j] * ex[b][lane * 8 + j];
        s[b] = waveSum(x);
    }
    if (lane < 16) u[((size_t)l * 16 + lane) * 512 + row] = s[lane];
}

// cb[l*16+b] = dot(extra[b], bk[l])
__global__ __launch_bounds__(256) void cbk_k(
    const float* __restrict__ bk, const float* __restrict__ extra,
    float* __restrict__ cb)
{
    const int gw = blockIdx.x * 4 + (threadIdx.x >> 6);
    const int lane = threadIdx.x & 63;
    const int l = gw >> 4, b = gw & 15;
    float s = 0.f;
#pragma unroll
    for (int j = 0; j < 8; ++j)
        s += extra[b * 512 + lane * 8 + j] * bk[l * 512 + lane * 8 + j];
    s = waveSum(s);
    if (lane == 0) cb[gw] = s;
}

// feat fp32 -> bf16, fused with aff for all 3 layers
__global__ __launch_bounds__(256) void cvt16_aff_k(
    const float* __restrict__ feat, u16* __restrict__ dst,
    const float* __restrict__ u, const float* __restrict__ cb,
    float* __restrict__ affb, float* __restrict__ affs_out)
{
    const int t = blockIdx.x * 256 + threadIdx.x;
    const long i = (long)t * 8;
    const int lane = threadIdx.x & 63;
    const int r = t >> 6;
    const int b = r >> 12;
    const float4 a0 = *(const float4*)(feat + i);
    const float4 a1 = *(const float4*)(feat + i + 4);
    short8 o;
    o[0] = (short)f2b(a0.x); o[1] = (short)f2b(a0.y);
    o[2] = (short)f2b(a0.z); o[3] = (short)f2b(a0.w);
    o[4] = (short)f2b(a1.x); o[5] = (short)f2b(a1.y);
    o[6] = (short)f2b(a1.z); o[7] = (short)f2b(a1.w);
    *(short8*)(dst + i) = o;
    const float f[8] = {a0.x, a0.y, a0.z, a0.w, a1.x, a1.y, a1.z, a1.w};
#pragma unroll
    for (int l = 0; l < 3; ++l) {
        const float* ur = u + ((size_t)l * 16 + b) * 512 + lane * 8;
        float s = 0.f;
#pragma unroll
        for (int j = 0; j < 8; ++j) s += f[j] * ur[j];
        s = waveSum(s);
        if (lane == 0) {
            const float av = 1.f / (1.f + __expf(-0.015625f * (s + cb[l * 16 + b])));
            affb[l * 65536 + r] = av;
            affs_out[l * 65536 + r] = av;
        }
    }
}

// x = LN(x + add; g, beta)
template<bool WRITE_OUT>
__global__ __launch_bounds__(256) void ln_k(
    float* __restrict__ x, const float* __restrict__ add,
    const float* __restrict__ g, const float* __restrict__ be,
    u16* __restrict__ x16, float* __restrict__ outp)
{
    const int r = blockIdx.x, t = threadIdx.x;
    const int w = t >> 6, lane = t & 63;
    __shared__ float red[4];
    float* xr = x + (long)r * 512;
    const float* ar = add + (long)r * 512;
    const float v0 = xr[2 * t]     + ar[2 * t];
    const float v1 = xr[2 * t + 1] + ar[2 * t + 1];
    float s = waveSum(v0 + v1);
    if (lane == 0) red[w] = s;
    __syncthreads();
    s = red[0] + red[1] + red[2] + red[3];
    const float mu = s * (1.f / 512.f);
    const float d0 = v0 - mu, d1 = v1 - mu;
    __syncthreads();
    float vs = waveSum(d0 * d0 + d1 * d1);
    if (lane == 0) red[w] = vs;
    __syncthreads();
    vs = red[0] + red[1] + red[2] + red[3];
    const float rs = rsqrtf(vs * (1.f / 512.f) + 1e-5f);
    const float o0 = g[2 * t]     * d0 * rs + be[2 * t];
    const float o1 = g[2 * t + 1] * d1 * rs + be[2 * t + 1];
    xr[2 * t] = o0; xr[2 * t + 1] = o1;
    x16[(long)r * 512 + 2 * t]     = f2b(o0);
    x16[(long)r * 512 + 2 * t + 1] = f2b(o1);
    if constexpr (WRITE_OUT) {
        outp[(long)r * 512 + 2 * t]     = o0;
        outp[(long)r * 512 + 2 * t + 1] = o1;
    }
}

// x = copy(queries) fp32 + bf16
__global__ __launch_bounds__(256) void initx_k(
    const float* __restrict__ src, float* __restrict__ x, u16* __restrict__ x16)
{
    const long i = ((long)blockIdx.x * 256 + threadIdx.x) * 8;
    const float4 a = *(const float4*)(src + i);
    const float4 b = *(const float4*)(src + i + 4);
    *(float4*)(x + i) = a;
    *(float4*)(x + i + 4) = b;
    short8 r;
    r[0] = (short)f2b(a.x); r[1] = (short)f2b(a.y); r[2] = (short)f2b(a.z); r[3] = (short)f2b(a.w);
    r[4] = (short)f2b(b.x); r[5] = (short)f2b(b.y); r[6] = (short)f2b(b.z); r[7] = (short)f2b(b.w);
    *(short8*)(x16 + i) = r;
}

// W (K,N) fp32 -> WT (N,K) bf16, batched over blockIdx.z
__global__ __launch_bounds__(256) void transpose_w_k(
    const float* __restrict__ W, u16* __restrict__ WT, int K, int N)
{
    __shared__ float tile[32][33];
    const int z = blockIdx.z;
    W  += (size_t)z * K * N;
    WT += (size_t)z * K * N;
    const int n0 = blockIdx.x * 32, k0 = blockIdx.y * 32;
    const int tx = threadIdx.x & 31, ty = threadIdx.x >> 5;
#pragma unroll
    for (int j = 0; j < 32; j += 8)
        tile[ty + j][tx] = W[(size_t)(k0 + ty + j) * N + n0 + tx];
    __syncthreads();
#pragma unroll
    for (int j = 0; j < 32; j += 8)
        WT[(size_t)(n0 + ty + j) * K + k0 + tx] = f2b(tile[tx][ty + j]);
}

// ---------------------------------------------------------------------------
extern "C" void kernel_launch(void* const* d_in, const int* in_sizes, int n_in,
                              void* d_out, int out_size, void* d_ws, size_t ws_size,
                              hipStream_t stream)
{
    (void)in_sizes; (void)n_in; (void)out_size; (void)ws_size;
    const float* queries = (const float*)d_in[0];
    const float* feat    = (const float*)d_in[1];
    const float* extra   = (const float*)d_in[2];
    const float* Wq = (const float*)d_in[3];  const float* bq = (const float*)d_in[4];
    const float* Wk = (const float*)d_in[5];  const float* bk = (const float*)d_in[6];
    const float* Wv = (const float*)d_in[7];  const float* bv = (const float*)d_in[8];
    const float* Wo = (const float*)d_in[9];  const float* bo = (const float*)d_in[10];
    const float* W1 = (const float*)d_in[11]; const float* b1 = (const float*)d_in[12];
    const float* W2 = (const float*)d_in[13]; const float* b2 = (const float*)d_in[14];
    const float* g2 = (const float*)d_in[15]; const float* be2 = (const float*)d_in[16];
    const float* g3 = (const float*)d_in[17]; const float* be3 = (const float*)d_in[18];

    char* wsb = (char*)d_ws;
    size_t off = 0;
    auto alloc = [&](size_t bytes) -> char* {
        char* p = wsb + off; off += (bytes + 255) & ~(size_t)255; return p;
    };
    u16*  feat16 = (u16*)alloc(33554432ull * 2);   // (B*Nk, C) bf16
    u16*  WqT = (u16*)alloc(786432ull * 2);
    u16*  WkT = (u16*)alloc(786432ull * 2);
    u16*  WvT = (u16*)alloc(786432ull * 2);
    u16*  WoT = (u16*)alloc(786432ull * 2);
    u16*  W1T = (u16*)alloc(3145728ull * 2);
    u16*  W2T = (u16*)alloc(3145728ull * 2);
    u16*  K16 = (u16*)alloc(33554432ull * 2);      // (B,Nk,C)
    u16*  VT16 = (u16*)alloc(33554432ull * 2);     // (B,C,Nk); later FF2 partials
    u16*  q16 = (u16*)alloc(524288ull * 2);        // (B*Nq, C)
    float* Op  = (float*)alloc(4194304ull * 4);    // flash partials (4,128,64,64)
    float2* ml = (float2*)alloc(32768ull * 8);     // (4,128,64)
    float* affb  = (float*)alloc(196608ull * 4);
    u16*  o16 = (u16*)alloc(524288ull * 2);
    float* oproj = (float*)alloc(524288ull * 4);
    float* xb    = (float*)alloc(524288ull * 4);
    u16*  x16 = (u16*)alloc(524288ull * 2);
    u16*  h116 = (u16*)alloc(2097152ull * 2);
    float* ffb   = (float*)alloc(524288ull * 4);
    float* uvec  = (float*)alloc(24576ull * 4);
    float* cb    = (float*)alloc(48ull * 4);
    float* part2 = (float*)VT16;                   // alias: VT dead after flash

    float* out_f = (float*)d_out;
    float* outs_base  = out_f;                     // (3,16,64,512)
    float* attns_base = out_f + 1572864;           // (3,16,64,4096)
    float* affs_base  = out_f + 14155776;          // (3,16,1,1,4096)

    // prep (layer-independent)
    umat_k<<<dim3(3, 128), 256, 0, stream>>>(Wk, extra, uvec);
    cbk_k<<<12, 256, 0, stream>>>(bk, extra, cb);
    cvt16_aff_k<<<16384, 256, 0, stream>>>(feat, feat16, uvec, cb, affb, affs_base);
    initx_k<<<256, 256, 0, stream>>>(queries, xb, x16);
    transpose_w_k<<<dim3(16, 16, 3), 256, 0, stream>>>(Wq, WqT, 512, 512);
    transpose_w_k<<<dim3(16, 16, 3), 256, 0, stream>>>(Wk, WkT, 512, 512);
    transpose_w_k<<<dim3(16, 16, 3), 256, 0, stream>>>(Wv, WvT, 512, 512);
    transpose_w_k<<<dim3(16, 16, 3), 256, 0, stream>>>(Wo, WoT, 512, 512);
    transpose_w_k<<<dim3(64, 16, 3), 256, 0, stream>>>(W1, W1T, 512, 2048);
    transpose_w_k<<<dim3(16, 64, 3), 256, 0, stream>>>(W2, W2T, 2048, 512);

    for (int i = 0; i < 3; ++i) {
        // K = feat @ Wk + bk -> bf16 (B,Nk,C)
        gemm256x256_k<false, true, false><<<dim3(2, 256, 1), 512, 0, stream>>>(
            feat16, WkT + i * 262144, bk + i * 512, K16,
            512, 512, 512, 0, 0, 0, nullptr);
        // VT' = aff ⊙ ((feat @ Wv)^T + bv) -> (B,C,Nk)
        gemm256x256_k<true, true, true><<<dim3(16, 2, 16), 512, 0, stream>>>(
            WvT + i * 262144, feat16, bv + i * 512, VT16,
            512, 512, 4096, 0, 2097152, 2097152, affb + i * 65536);
        // q = x @ Wq + bq (raw)
        gemm_bt_k<64, 64, true, false, false, true>
            <<<dim3(8, 16, 1), 256, 0, stream>>>(
            x16, WqT + i * 262144, bq + i * 512, q16,
            512, 512, 512, 512, 0, 0, 0, 1.f);
        // attns[b] = (SCALE/8) q[b] @ K[b]^T -> fp32 (16,64,4096)
        gemm_bt_k<64, 128, false, false, false, false>
            <<<dim3(32, 1, 16), 256, 0, stream>>>(
            q16, K16, nullptr, attns_base + (size_t)i * 4194304,
            512, 512, 512, 4096, 32768, 2097152, 262144, 0.015625f);
        // flash attention (4 kv-splits) + merge -> o16
        fattn_k<<<dim3(4, 128), 256, 0, stream>>>(q16, K16, VT16, Op, ml);
        fmerge_k<<<512, 256, 0, stream>>>(Op, ml, o16);
        // o @ Wo + bo -> fp32
        gemm_bt_k<64, 64, false, false, false, true>
            <<<dim3(8, 16, 1), 256, 0, stream>>>(
            o16, WoT + i * 262144, bo + i * 512, oproj,
            512, 512, 512, 512, 0, 0, 0, 1.f);
        // x = LN(x + oproj; g2, beta2)
        ln_k<false><<<1024, 256, 0, stream>>>(xb, oproj, g2 + i * 512, be2 + i * 512, x16, nullptr);
        // h1 = relu(x @ W1 + b1) -> bf16
        gemm_bt_k<64, 128, true, true, false, true>
            <<<dim3(16, 16, 1), 256, 0, stream>>>(
            x16, W1T + (size_t)i * 1048576, b1 + i * 2048, h116,
            512, 512, 512, 2048, 0, 0, 0, 1.f);
        // ff partials = h1 @ W2 (split-K 4)
        gemm_bt_k<64, 64, false, false, false, false>
            <<<dim3(8, 16, 4), 256, 0, stream>>>(
            h116, W2T + (size_t)i * 1048576, nullptr, part2,
            512, 2048, 2048, 512, 512, 512, 524288, 1.f);
        ffred_k<<<512, 256, 0, stream>>>(part2, b2 + i * 512, ffb);
        // x = LN(x + ff; g3, beta3), write outs[i]
        ln_k<true><<<1024, 256, 0, stream>>>(xb, ffb, g3 + i * 512, be3 + i * 512, x16,
                                             outs_base + (size_t)i * 524288);
    }
}

// Round 11
// 660.308 us; speedup vs baseline: 1.0429x; 1.0429x over previous
//
#include <hip/hip_runtime.h>

// SegDecoder: 3-layer cross-attention decoder on MI355X (gfx950).
// B=16, Nq=64, Nk=4096, C=512, H=8, hd=64, FF=2048, L=3.
// R11: big-GEMM = 256^2 tile with K-HALF ring (4 slots x 32 cols), 4 fine
// phases/K-tile, COUNTED vmcnt(8) (never 0 in steady loop) + raw s_barrier.
// This is the counted+interleaved cell (m218) that R7 (counted only) and
// R10 (interleave+drain, regressed) each lacked. Attention stays R9-flash.

typedef unsigned short u16;
typedef __attribute__((ext_vector_type(8))) short short8;
typedef __attribute__((ext_vector_type(4))) short short4v;
typedef __attribute__((ext_vector_type(4))) float f32x4;

__device__ __forceinline__ float b2f(u16 u) {
    union { unsigned int i; float f; } v; v.i = ((unsigned int)u) << 16; return v.f;
}
__device__ __forceinline__ u16 f2b(float f) {  // round-to-nearest-even
    unsigned int x = __float_as_uint(f);
    x += 0x7fffu + ((x >> 16) & 1u);
    return (u16)(x >> 16);
}

__device__ __forceinline__ float waveSum(float v) {
#pragma unroll
    for (int o = 32; o > 0; o >>= 1) v += __shfl_xor(v, o);
    return v;
}

// async global->LDS, 16B per lane. LDS dest is wave-uniform base + lane*16.
__device__ __forceinline__ void gl_lds16(const void* g, void* l) {
    __builtin_amdgcn_global_load_lds(
        (__attribute__((address_space(1))) void*)g,
        (__attribute__((address_space(3))) void*)l, 16, 0, 0);
}

// ---------------------------------------------------------------------------
// Big-GEMM (Kproj / VT): C = A(M,512) @ Bt(N,512)^T, BM=BN=256, 8 waves
// (2M x 4N), per-wave C = 128x64. K split into 16 K-HALVES of 32 cols;
// LDS ring of 4 K-half slots (Ah[4][256][32] + Bh[4][256][32] = 128KB).
// Tile t consumes slots (2t)&3 [phases p0,p1 = kc0] and (2t+1)&3 [p2,p3 = kc1];
// stages K-half 2t+3 during p0/p1 and 2t+4 during p2/p3 (2 gl_lds per wave
// per phase). Waits: vmcnt(8)+s_barrier at p1/p3 end (12 outstanding -> drain
// oldest K-half, keep 8 in flight); tail: t=6 p3 -> vmcnt(4), t=7 p1 ->
// vmcnt(0), t=7 p3 -> none. Swizzle u^((row>>2)&3): 2-way ds_read (free),
// same involution on gl_lds source. XCD-chunk block swizzle (R8-proven).
// ---------------------------------------------------------------------------
template<bool BIAS_ROW, bool HAS_BIAS, bool AFFC>
__global__ __launch_bounds__(512, 1) void gemm256v2_k(
    const u16* __restrict__ A, const u16* __restrict__ Bt,
    const float* __restrict__ bias, u16* __restrict__ Cout,
    int lda, int ldb, int ldc, long sA2, long sB2, long sC2,
    const float* __restrict__ affc)
{
    __shared__ u16 Ah[4][256][32];   // 64 KB
    __shared__ u16 Bh[4][256][32];   // 64 KB
    const int tid = threadIdx.x;
    const int lane = tid & 63;
    const int wave = tid >> 6;        // 0..7

    // bijective XCD-chunk swizzle (m204)
    const int gx = gridDim.x, gy = gridDim.y;
    const int nwg = gx * gy * gridDim.z;
    int id;
    {
        const int orig = blockIdx.x + blockIdx.y * gx + blockIdx.z * gx * gy;
        const int qq = nwg >> 3, rr = nwg & 7;
        const int xcd = orig & 7, sub = orig >> 3;
        id = (xcd < rr ? xcd * (qq + 1) : rr * (qq + 1) + (xcd - rr) * qq) + sub;
    }
    const int bx = id % gx;
    const int by = (id / gx) % gy;
    const int z  = id / (gx * gy);

    A  += (long)z * sA2;
    Bt += (long)z * sB2;
    const long cbase = (long)z * sC2;
    const int n0 = bx * 256;
    const int m0 = by * 256;
    const int wm = wave >> 2;         // 0..1 (128-row A slab)
    const int wn = wave & 3;          // 0..3 (64-row B slab)
    const int rl = lane & 15;
    const int uq = lane >> 4;         // 0..3: 16B unit within 32-col row
    const int srow = lane >> 2;       // 0..15
    const int up   = lane & 3;

    f32x4 acc[8][4];
#pragma unroll
    for (int i = 0; i < 8; ++i)
#pragma unroll
        for (int j = 0; j < 4; ++j) acc[i][j] = (f32x4){0.f, 0.f, 0.f, 0.f};

    // one round = 1KB = 16 rows x 64B; K-half h = 4 rounds/wave (2 A + 2 B)
    auto stage_round = [&](int h, int r) {
        const int slot = h & 3;
        const int k0 = h * 32;
        if (r < 2) {
            const int row = r * 128 + wave * 16 + srow;
            const int ul = up ^ ((row >> 2) & 3);
            gl_lds16(A + (long)(m0 + row) * lda + k0 + ul * 8,
                     &Ah[slot][r * 128 + wave * 16][0]);
        } else {
            const int row = (r - 2) * 128 + wave * 16 + srow;
            const int ul = up ^ ((row >> 2) & 3);
            gl_lds16(Bt + (long)(n0 + row) * ldb + k0 + ul * 8,
                     &Bh[slot][(r - 2) * 128 + wave * 16][0]);
        }
    };

    // prologue: K-halves 0,1,2 (12 loads/wave); drain oldest 4 (K-half 0)
#pragma unroll
    for (int h = 0; h < 3; ++h)
#pragma unroll
        for (int r = 0; r < 4; ++r) stage_round(h, r);
    asm volatile("s_waitcnt vmcnt(8)\n\ts_barrier" ::: "memory");

#pragma unroll
    for (int t = 0; t < 8; ++t) {
        const int s0 = (2 * t) & 3, s1 = (2 * t + 1) & 3;
        const int hA = 2 * t + 3, hB = 2 * t + 4;
        short8 bf[4], af[4];

        // ---- p0: kc0, M-frags 0-3 ----
        if (hA < 16) { stage_round(hA, 0); stage_round(hA, 1); }
#pragma unroll
        for (int j = 0; j < 4; ++j) {
            const int R = wn * 64 + j * 16 + rl;
            bf[j] = *(const short8*)(&Bh[s0][R][(uq ^ ((R >> 2) & 3)) * 8]);
        }
#pragma unroll
        for (int i = 0; i < 4; ++i) {
            const int R = wm * 128 + i * 16 + rl;
            af[i] = *(const short8*)(&Ah[s0][R][(uq ^ ((R >> 2) & 3)) * 8]);
        }
        __builtin_amdgcn_s_setprio(1);
#pragma unroll
        for (int i = 0; i < 4; ++i)
#pragma unroll
            for (int j = 0; j < 4; ++j)
                acc[i][j] = __builtin_amdgcn_mfma_f32_16x16x32_bf16(
                    af[i], bf[j], acc[i][j], 0, 0, 0);
        __builtin_amdgcn_s_setprio(0);

        // ---- p1: kc0, M-frags 4-7 ----
        if (hA < 16) { stage_round(hA, 2); stage_round(hA, 3); }
#pragma unroll
        for (int i = 0; i < 4; ++i) {
            const int R = wm * 128 + (4 + i) * 16 + rl;
            af[i] = *(const short8*)(&Ah[s0][R][(uq ^ ((R >> 2) & 3)) * 8]);
        }
        __builtin_amdgcn_s_setprio(1);
#pragma unroll
        for (int i = 0; i < 4; ++i)
#pragma unroll
            for (int j = 0; j < 4; ++j)
                acc[4 + i][j] = __builtin_amdgcn_mfma_f32_16x16x32_bf16(
                    af[i], bf[j], acc[4 + i][j], 0, 0, 0);
        __builtin_amdgcn_s_setprio(0);
        if (t < 7) asm volatile("s_waitcnt vmcnt(8)\n\ts_barrier" ::: "memory");
        else       asm volatile("s_waitcnt vmcnt(0)\n\ts_barrier" ::: "memory");

        // ---- p2: kc1, M-frags 0-3 ----
        if (hB < 16) { stage_round(hB, 0); stage_round(hB, 1); }
#pragma unroll
        for (int j = 0; j < 4; ++j) {
            const int R = wn * 64 + j * 16 + rl;
            bf[j] = *(const short8*)(&Bh[s1][R][(uq ^ ((R >> 2) & 3)) * 8]);
        }
#pragma unroll
        for (int i = 0; i < 4; ++i) {
            const int R = wm * 128 + i * 16 + rl;
            af[i] = *(const short8*)(&Ah[s1][R][(uq ^ ((R >> 2) & 3)) * 8]);
        }
        __builtin_amdgcn_s_setprio(1);
#pragma unroll
        for (int i = 0; i < 4; ++i)
#pragma unroll
            for (int j = 0; j < 4; ++j)
                acc[i][j] = __builtin_amdgcn_mfma_f32_16x16x32_bf16(
                    af[i], bf[j], acc[i][j], 0, 0, 0);
        __builtin_amdgcn_s_setprio(0);

        // ---- p3: kc1, M-frags 4-7 ----
        if (hB < 16) { stage_round(hB, 2); stage_round(hB, 3); }
#pragma unroll
        for (int i = 0; i < 4; ++i) {
            const int R = wm * 128 + (4 + i) * 16 + rl;
            af[i] = *(const short8*)(&Ah[s1][R][(uq ^ ((R >> 2) & 3)) * 8]);
        }
        __builtin_amdgcn_s_setprio(1);
#pragma unroll
        for (int i = 0; i < 4; ++i)
#pragma unroll
            for (int j = 0; j < 4; ++j)
                acc[4 + i][j] = __builtin_amdgcn_mfma_f32_16x16x32_bf16(
                    af[i], bf[j], acc[4 + i][j], 0, 0, 0);
        __builtin_amdgcn_s_setprio(0);
        if (t < 6)       asm volatile("s_waitcnt vmcnt(8)\n\ts_barrier" ::: "memory");
        else if (t == 6) asm volatile("s_waitcnt vmcnt(4)\n\ts_barrier" ::: "memory");
        // t == 7: no wait needed (epilogue uses registers only)
    }

    const int r0 = (lane >> 4) * 4;
    const int c0 = lane & 15;
#pragma unroll
    for (int i = 0; i < 8; ++i) {
#pragma unroll
        for (int j = 0; j < 4; ++j) {
#pragma unroll
            for (int r = 0; r < 4; ++r) {
                const int row = m0 + wm * 128 + i * 16 + r0 + r;
                const int col = n0 + wn * 64 + j * 16 + c0;
                float v = acc[i][j][r];
                if constexpr (HAS_BIAS) {
                    if constexpr (BIAS_ROW) v += bias[row]; else v += bias[col];
                }
                if constexpr (AFFC) v *= affc[(long)z * 4096 + col];
                Cout[cbase + (long)row * ldc + col] = f2b(v);
            }
        }
    }
}

// ---------------------------------------------------------------------------
// Flash attention partial (R9, proven): block = (split, bh).
// ---------------------------------------------------------------------------
__global__ __launch_bounds__(256) void fattn_k(
    const u16* __restrict__ q16, const u16* __restrict__ K16,
    const u16* __restrict__ VT16, float* __restrict__ Op,
    float2* __restrict__ ml)
{
    __shared__ u16 Qs[64][64];
    __shared__ u16 Ks[128][64];
    __shared__ u16 Vs[64][128];
    __shared__ u16 Ps[64][128];
    const int t = threadIdx.x;
    const int lane = t & 63;
    const int w = t >> 6;
    const int bh = blockIdx.y;
    const int split = blockIdx.x;
    const int b = bh >> 3, h = bh & 7;
    const int kbase = split * 1024;
    const int rl = lane & 15, uq = lane >> 4;
    const int r0 = (lane >> 4) * 4;
    const int c0 = lane & 15;
    const int srow8 = lane >> 3, up8 = lane & 7;
    const int srow4 = lane >> 4, up16 = lane & 15;

#pragma unroll
    for (int rnd = 0; rnd < 2; ++rnd) {
        const int row = rnd * 32 + w * 8 + srow8;
        const int ul = up8 ^ (row & 7);
        gl_lds16(q16 + ((long)(b * 64 + row)) * 512 + h * 64 + ul * 8,
                 &Qs[rnd * 32 + w * 8][0]);
    }

    f32x4 O[4];
#pragma unroll
    for (int n = 0; n < 4; ++n) O[n] = (f32x4){0.f, 0.f, 0.f, 0.f};
    float m_run[4] = {-3.0e38f, -3.0e38f, -3.0e38f, -3.0e38f};
    float l_run[4] = {0.f, 0.f, 0.f, 0.f};

    const int R = w * 16 + rl;

    for (int tt = 0; tt < 8; ++tt) {
        __syncthreads();
#pragma unroll
        for (int rnd = 0; rnd < 4; ++rnd) {
            const int row = rnd * 32 + w * 8 + srow8;
            const int ul = up8 ^ (row & 7);
            gl_lds16(K16 + ((long)(b * 4096 + kbase + tt * 128 + row)) * 512
                         + h * 64 + ul * 8,
                     &Ks[rnd * 32 + w * 8][0]);
        }
#pragma unroll
        for (int rnd = 0; rnd < 4; ++rnd) {
            const int row = rnd * 16 + w * 4 + srow4;
            const int ul = up16 ^ (row & 15);
            gl_lds16(VT16 + (long)b * 2097152 + ((long)(h * 64 + row)) * 4096
                         + kbase + tt * 128 + ul * 8,
                     &Vs[rnd * 16 + w * 4][0]);
        }
        __syncthreads();

        f32x4 s[8];
        short8 af[2];
#pragma unroll
        for (int kc = 0; kc < 2; ++kc)
            af[kc] = *(const short8*)(&Qs[R][((kc * 4 + uq) ^ (R & 7)) * 8]);
#pragma unroll
        for (int j = 0; j < 8; ++j) {
            s[j] = (f32x4){0.f, 0.f, 0.f, 0.f};
            const int Rb = j * 16 + rl;
#pragma unroll
            for (int kc = 0; kc < 2; ++kc) {
                short8 bf = *(const short8*)(&Ks[Rb][((kc * 4 + uq) ^ (Rb & 7)) * 8]);
                s[j] = __builtin_amdgcn_mfma_f32_16x16x32_bf16(af[kc], bf, s[j], 0, 0, 0);
            }
        }
#pragma unroll
        for (int j = 0; j < 8; ++j)
#pragma unroll
            for (int r = 0; r < 4; ++r) s[j][r] *= 0.125f;

        float mv[4];
#pragma unroll
        for (int r = 0; r < 4; ++r) {
            float m = s[0][r];
#pragma unroll
            for (int j = 1; j < 8; ++j) m = fmaxf(m, s[j][r]);
#pragma unroll
            for (int mask = 1; mask < 16; mask <<= 1)
                m = fmaxf(m, __shfl_xor(m, mask));
            mv[r] = m;
        }
        float al[4], rs[4];
#pragma unroll
        for (int r = 0; r < 4; ++r) {
            const float mn = fmaxf(m_run[r], mv[r]);
            al[r] = __expf(m_run[r] - mn);
            m_run[r] = mn;
            rs[r] = 0.f;
        }
#pragma unroll
        for (int j = 0; j < 8; ++j)
#pragma unroll
            for (int r = 0; r < 4; ++r) {
                s[j][r] = __expf(s[j][r] - m_run[r]);
                rs[r] += s[j][r];
            }
#pragma unroll
        for (int r = 0; r < 4; ++r) {
#pragma unroll
            for (int mask = 1; mask < 16; mask <<= 1)
                rs[r] += __shfl_xor(rs[r], mask);
            l_run[r] = l_run[r] * al[r] + rs[r];
        }
#pragma unroll
        for (int n = 0; n < 4; ++n)
#pragma unroll
            for (int r = 0; r < 4; ++r) O[n][r] *= al[r];

#pragma unroll
        for (int j = 0; j < 8; ++j)
#pragma unroll
            for (int r = 0; r < 4; ++r) {
                const int row = w * 16 + r0 + r;
                const int col = j * 16 + c0;
                Ps[row][(((col >> 3) ^ (row & 15)) << 3) + (col & 7)] = f2b(s[j][r]);
            }
#pragma unroll
        for (int kc4 = 0; kc4 < 4; ++kc4) {
            const short8 afp = *(const short8*)(&Ps[R][(((kc4 * 4 + uq) ^ (R & 15)) << 3)]);
#pragma unroll
            for (int n = 0; n < 4; ++n) {
                const int Rv = n * 16 + rl;
                const short8 bfv = *(const short8*)(&Vs[Rv][(((kc4 * 4 + uq) ^ (Rv & 15)) << 3)]);
                O[n] = __builtin_amdgcn_mfma_f32_16x16x32_bf16(afp, bfv, O[n], 0, 0, 0);
            }
        }
    }

    const long obase = ((long)(split * 128 + bh)) * 64;
#pragma unroll
    for (int n = 0; n < 4; ++n)
#pragma unroll
        for (int r = 0; r < 4; ++r) {
            const int q = w * 16 + r0 + r;
            Op[(obase + q) * 64 + n * 16 + c0] = O[n][r];
        }
    if (c0 == 0) {
#pragma unroll
        for (int r = 0; r < 4; ++r) {
            const int q = w * 16 + r0 + r;
            ml[obase + q] = make_float2(m_run[r], l_run[r]);
        }
    }
}

// merge 4 flash splits -> o16 (B,Nq,C)
__global__ __launch_bounds__(256) void fmerge_k(
    const float* __restrict__ Op, const float2* __restrict__ ml,
    u16* __restrict__ o16)
{
    const int i = blockIdx.x * 256 + threadIdx.x;
    const int d4 = i & 15;
    const int q  = (i >> 4) & 63;
    const int bh = i >> 10;
    const float2 m0 = ml[((long)(0 * 128 + bh)) * 64 + q];
    const float2 m1 = ml[((long)(1 * 128 + bh)) * 64 + q];
    const float2 m2 = ml[((long)(2 * 128 + bh)) * 64 + q];
    const float2 m3 = ml[((long)(3 * 128 + bh)) * 64 + q];
    const float m = fmaxf(fmaxf(m0.x, m1.x), fmaxf(m2.x, m3.x));
    const float e0 = __expf(m0.x - m), e1 = __expf(m1.x - m);
    const float e2 = __expf(m2.x - m), e3 = __expf(m3.x - m);
    const float inv = 1.f / (m0.y * e0 + m1.y * e1 + m2.y * e2 + m3.y * e3);
    const float4 v0 = *(const float4*)(Op + (((long)(0 * 128 + bh)) * 64 + q) * 64 + d4 * 4);
    const float4 v1 = *(const float4*)(Op + (((long)(1 * 128 + bh)) * 64 + q) * 64 + d4 * 4);
    const float4 v2 = *(const float4*)(Op + (((long)(2 * 128 + bh)) * 64 + q) * 64 + d4 * 4);
    const float4 v3 = *(const float4*)(Op + (((long)(3 * 128 + bh)) * 64 + q) * 64 + d4 * 4);
    float4 acc;
    acc.x = (v0.x * e0 + v1.x * e1 + v2.x * e2 + v3.x * e3) * inv;
    acc.y = (v0.y * e0 + v1.y * e1 + v2.y * e2 + v3.y * e3) * inv;
    acc.z = (v0.z * e0 + v1.z * e1 + v2.z * e2 + v3.z * e3) * inv;
    acc.w = (v0.w * e0 + v1.w * e1 + v2.w * e2 + v3.w * e3) * inv;
    const int b = bh >> 3, h = bh & 7;
    short4v r;
    r[0] = (short)f2b(acc.x); r[1] = (short)f2b(acc.y);
    r[2] = (short)f2b(acc.z); r[3] = (short)f2b(acc.w);
    *(short4v*)(o16 + (long)b * 32768 + q * 512 + h * 64 + d4 * 4) = r;
}

// ---------------------------------------------------------------------------
// Generic batched GEMM: C = alpha*A@Bt^T [+bias][relu]; BK=64 single-buffered.
// ---------------------------------------------------------------------------
template<int TM, int TN, bool OUT_BF16, bool RELU, bool BIAS_ROW, bool HAS_BIAS>
__global__ __launch_bounds__(256) void gemm_bt_k(
    const u16* __restrict__ A, const u16* __restrict__ Bt,
    const float* __restrict__ bias, void* __restrict__ Cout,
    int K, int lda, int ldb, int ldc,
    long sA1, long sB1, long sC1, float alpha)
{
    __shared__ u16 As[TM][64];
    __shared__ u16 Bs[TN][64];
    const int t = threadIdx.x;
    const int lane = t & 63;
    const int wave = t >> 6;
    const int z = blockIdx.z;
    A  += (long)z * sA1;
    Bt += (long)z * sB1;
    const long cbase = (long)z * sC1;
    const int n0 = blockIdx.x * TN;
    const int m0 = blockIdx.y * TM;
    constexpr int FM = TM / 32, FN = TN / 32;
    const int wr = wave >> 1, wc = wave & 1;
    const int rl = lane & 15, uq = lane >> 4;

    f32x4 acc[FM][FN];
#pragma unroll
    for (int i = 0; i < FM; ++i)
#pragma unroll
        for (int j = 0; j < FN; ++j) acc[i][j] = (f32x4){0.f, 0.f, 0.f, 0.f};

    const int srow = lane >> 3;
    const int up   = lane & 7;

    for (int k0 = 0; k0 < K; k0 += 64) {
        __syncthreads();
#pragma unroll
        for (int r = 0; r < TM / 32; ++r) {
            const int br = (wave * (TM / 32) + r) * 8;
            const int row = br + srow;
            const int ul = up ^ (row & 7);
            gl_lds16(A + (long)(m0 + row) * lda + k0 + ul * 8, &As[br][0]);
        }
#pragma unroll
        for (int r = 0; r < TN / 32; ++r) {
            const int br = (wave * (TN / 32) + r) * 8;
            const int row = br + srow;
            const int ul = up ^ (row & 7);
            gl_lds16(Bt + (long)(n0 + row) * ldb + k0 + ul * 8, &Bs[br][0]);
        }
        __syncthreads();

#pragma unroll
        for (int kc = 0; kc < 2; ++kc) {
            short8 af[FM], bf[FN];
#pragma unroll
            for (int i = 0; i < FM; ++i) {
                const int R = wr * (TM / 2) + i * 16 + rl;
                af[i] = *(const short8*)(&As[R][((kc * 4 + uq) ^ (R & 7)) * 8]);
            }
#pragma unroll
            for (int j = 0; j < FN; ++j) {
                const int R = wc * (TN / 2) + j * 16 + rl;
                bf[j] = *(const short8*)(&Bs[R][((kc * 4 + uq) ^ (R & 7)) * 8]);
            }
#pragma unroll
            for (int i = 0; i < FM; ++i)
#pragma unroll
                for (int j = 0; j < FN; ++j)
                    acc[i][j] = __builtin_amdgcn_mfma_f32_16x16x32_bf16(
                        af[i], bf[j], acc[i][j], 0, 0, 0);
        }
    }

    const int r0 = (lane >> 4) * 4;
    const int c0 = lane & 15;
#pragma unroll
    for (int i = 0; i < FM; ++i) {
#pragma unroll
        for (int j = 0; j < FN; ++j) {
#pragma unroll
            for (int r = 0; r < 4; ++r) {
                const int row = m0 + wr * (TM / 2) + i * 16 + r0 + r;
                const int col = n0 + wc * (TN / 2) + j * 16 + c0;
                float v = acc[i][j][r] * alpha;
                if constexpr (HAS_BIAS) {
                    if constexpr (BIAS_ROW) v += bias[row]; else v += bias[col];
                }
                if constexpr (RELU) v = fmaxf(v, 0.f);
                const long idx = cbase + (long)row * ldc + col;
                if constexpr (OUT_BF16) ((u16*)Cout)[idx] = f2b(v);
                else                    ((float*)Cout)[idx] = v;
            }
        }
    }
}

// split-K FF2 reduce + bias
__global__ __launch_bounds__(256) void ffred_k(
    const float* __restrict__ part, const float* __restrict__ bias,
    float* __restrict__ out)
{
    const int i = (blockIdx.x * 256 + threadIdx.x) * 4;
    const int c = i & 511;
    float4 s = *(const float4*)(part + i);
#pragma unroll
    for (int sp = 1; sp < 4; ++sp) {
        const float4 v = *(const float4*)(part + (long)sp * 524288 + i);
        s.x += v.x; s.y += v.y; s.z += v.z; s.w += v.w;
    }
    s.x += bias[c]; s.y += bias[c + 1]; s.z += bias[c + 2]; s.w += bias[c + 3];
    *(float4*)(out + i) = s;
}

// u[l][b][c'] = sum_c Wk[l][c'][c] * extra[b][c]
__global__ __launch_bounds__(256) void umat_k(
    const float* __restrict__ Wk, const float* __restrict__ extra,
    float* __restrict__ u)
{
    __shared__ float ex[16][512];
    const int l = blockIdx.x;
    const int t = threadIdx.x;
    for (int i = t; i < 16 * 512 / 4; i += 256)
        ((float4*)&ex[0][0])[i] = ((const float4*)extra)[i];
    __syncthreads();
    const int lane = t & 63, wave = t >> 6;
    const int row = blockIdx.y * 4 + wave;
    const float* wrow = Wk + ((size_t)l * 512 + row) * 512 + lane * 8;
    float w[8];
#pragma unroll
    for (int j = 0; j < 8; ++j) w[j] = wrow[j];
    float s[16];
#pragma unroll
    for (int b = 0; b < 16; ++b) {
        float x = 0.f;
#pragma unroll
        for (int j = 0; j < 8; ++j) x += w[j] * ex[b][lane * 8 + j];
        s[b] = waveSum(x);
    }
    if (lane < 16) u[((size_t)l * 16 + lane) * 512 + row] = s[lane];
}

// cb[l*16+b] = dot(extra[b], bk[l])
__global__ __launch_bounds__(256) void cbk_k(
    const float* __restrict__ bk, const float* __restrict__ extra,
    float* __restrict__ cb)
{
    const int gw = blockIdx.x * 4 + (threadIdx.x >> 6);
    const int lane = threadIdx.x & 63;
    const int l = gw >> 4, b = gw & 15;
    float s = 0.f;
#pragma unroll
    for (int j = 0; j < 8; ++j)
        s += extra[b * 512 + lane * 8 + j] * bk[l * 512 + lane * 8 + j];
    s = waveSum(s);
    if (lane == 0) cb[gw] = s;
}

// feat fp32 -> bf16, fused with aff for all 3 layers
__global__ __launch_bounds__(256) void cvt16_aff_k(
    const float* __restrict__ feat, u16* __restrict__ dst,
    const float* __restrict__ u, const float* __restrict__ cb,
    float* __restrict__ affb, float* __restrict__ affs_out)
{
    const int t = blockIdx.x * 256 + threadIdx.x;
    const long i = (long)t * 8;
    const int lane = threadIdx.x & 63;
    const int r = t >> 6;
    const int b = r >> 12;
    const float4 a0 = *(const float4*)(feat + i);
    const float4 a1 = *(const float4*)(feat + i + 4);
    short8 o;
    o[0] = (short)f2b(a0.x); o[1] = (short)f2b(a0.y);
    o[2] = (short)f2b(a0.z); o[3] = (short)f2b(a0.w);
    o[4] = (short)f2b(a1.x); o[5] = (short)f2b(a1.y);
    o[6] = (short)f2b(a1.z); o[7] = (short)f2b(a1.w);
    *(short8*)(dst + i) = o;
    const float f[8] = {a0.x, a0.y, a0.z, a0.w, a1.x, a1.y, a1.z, a1.w};
#pragma unroll
    for (int l = 0; l < 3; ++l) {
        const float* ur = u + ((size_t)l * 16 + b) * 512 + lane * 8;
        float s = 0.f;
#pragma unroll
        for (int j = 0; j < 8; ++j) s += f[j] * ur[j];
        s = waveSum(s);
        if (lane == 0) {
            const float av = 1.f / (1.f + __expf(-0.015625f * (s + cb[l * 16 + b])));
            affb[l * 65536 + r] = av;
            affs_out[l * 65536 + r] = av;
        }
    }
}

// x = LN(x + add; g, beta)
template<bool WRITE_OUT>
__global__ __launch_bounds__(256) void ln_k(
    float* __restrict__ x, const float* __restrict__ add,
    const float* __restrict__ g, const float* __restrict__ be,
    u16* __restrict__ x16, float* __restrict__ outp)
{
    const int r = blockIdx.x, t = threadIdx.x;
    const int w = t >> 6, lane = t & 63;
    __shared__ float red[4];
    float* xr = x + (long)r * 512;
    const float* ar = add + (long)r * 512;
    const float v0 = xr[2 * t]     + ar[2 * t];
    const float v1 = xr[2 * t + 1] + ar[2 * t + 1];
    float s = waveSum(v0 + v1);
    if (lane == 0) red[w] = s;
    __syncthreads();
    s = red[0] + red[1] + red[2] + red[3];
    const float mu = s * (1.f / 512.f);
    const float d0 = v0 - mu, d1 = v1 - mu;
    __syncthreads();
    float vs = waveSum(d0 * d0 + d1 * d1);
    if (lane == 0) red[w] = vs;
    __syncthreads();
    vs = red[0] + red[1] + red[2] + red[3];
    const float rs = rsqrtf(vs * (1.f / 512.f) + 1e-5f);
    const float o0 = g[2 * t]     * d0 * rs + be[2 * t];
    const float o1 = g[2 * t + 1] * d1 * rs + be[2 * t + 1];
    xr[2 * t] = o0; xr[2 * t + 1] = o1;
    x16[(long)r * 512 + 2 * t]     = f2b(o0);
    x16[(long)r * 512 + 2 * t + 1] = f2b(o1);
    if constexpr (WRITE_OUT) {
        outp[(long)r * 512 + 2 * t]     = o0;
        outp[(long)r * 512 + 2 * t + 1] = o1;
    }
}

// x = copy(queries) fp32 + bf16
__global__ __launch_bounds__(256) void initx_k(
    const float* __restrict__ src, float* __restrict__ x, u16* __restrict__ x16)
{
    const long i = ((long)blockIdx.x * 256 + threadIdx.x) * 8;
    const float4 a = *(const float4*)(src + i);
    const float4 b = *(const float4*)(src + i + 4);
    *(float4*)(x + i) = a;
    *(float4*)(x + i + 4) = b;
    short8 r;
    r[0] = (short)f2b(a.x); r[1] = (short)f2b(a.y); r[2] = (short)f2b(a.z); r[3] = (short)f2b(a.w);
    r[4] = (short)f2b(b.x); r[5] = (short)f2b(b.y); r[6] = (short)f2b(b.z); r[7] = (short)f2b(b.w);
    *(short8*)(x16 + i) = r;
}

// W (K,N) fp32 -> WT (N,K) bf16, batched over blockIdx.z
__global__ __launch_bounds__(256) void transpose_w_k(
    const float* __restrict__ W, u16* __restrict__ WT, int K, int N)
{
    __shared__ float tile[32][33];
    const int z = blockIdx.z;
    W  += (size_t)z * K * N;
    WT += (size_t)z * K * N;
    const int n0 = blockIdx.x * 32, k0 = blockIdx.y * 32;
    const int tx = threadIdx.x & 31, ty = threadIdx.x >> 5;
#pragma unroll
    for (int j = 0; j < 32; j += 8)
        tile[ty + j][tx] = W[(size_t)(k0 + ty + j) * N + n0 + tx];
    __syncthreads();
#pragma unroll
    for (int j = 0; j < 32; j += 8)
        WT[(size_t)(n0 + ty + j) * K + k0 + tx] = f2b(tile[tx][ty + j]);
}

// ---------------------------------------------------------------------------
extern "C" void kernel_launch(void* const* d_in, const int* in_sizes, int n_in,
                              void* d_out, int out_size, void* d_ws, size_t ws_size,
                              hipStream_t stream)
{
    (void)in_sizes; (void)n_in; (void)out_size; (void)ws_size;
    const float* queries = (const float*)d_in[0];
    const float* feat    = (const float*)d_in[1];
    const float* extra   = (const float*)d_in[2];
    const float* Wq = (const float*)d_in[3];  const float* bq = (const float*)d_in[4];
    const float* Wk = (const float*)d_in[5];  const float* bk = (const float*)d_in[6];
    const float* Wv = (const float*)d_in[7];  const float* bv = (const float*)d_in[8];
    const float* Wo = (const float*)d_in[9];  const float* bo = (const float*)d_in[10];
    const float* W1 = (const float*)d_in[11]; const float* b1 = (const float*)d_in[12];
    const float* W2 = (const float*)d_in[13]; const float* b2 = (const float*)d_in[14];
    const float* g2 = (const float*)d_in[15]; const float* be2 = (const float*)d_in[16];
    const float* g3 = (const float*)d_in[17]; const float* be3 = (const float*)d_in[18];

    char* wsb = (char*)d_ws;
    size_t off = 0;
    auto alloc = [&](size_t bytes) -> char* {
        char* p = wsb + off; off += (bytes + 255) & ~(size_t)255; return p;
    };
    u16*  feat16 = (u16*)alloc(33554432ull * 2);   // (B*Nk, C) bf16
    u16*  WqT = (u16*)alloc(786432ull * 2);
    u16*  WkT = (u16*)alloc(786432ull * 2);
    u16*  WvT = (u16*)alloc(786432ull * 2);
    u16*  WoT = (u16*)alloc(786432ull * 2);
    u16*  W1T = (u16*)alloc(3145728ull * 2);
    u16*  W2T = (u16*)alloc(3145728ull * 2);
    u16*  K16 = (u16*)alloc(33554432ull * 2);      // (B,Nk,C)
    u16*  VT16 = (u16*)alloc(33554432ull * 2);     // (B,C,Nk); later FF2 partials
    u16*  q16 = (u16*)alloc(524288ull * 2);        // (B*Nq, C)
    float* Op  = (float*)alloc(4194304ull * 4);    // flash partials (4,128,64,64)
    float2* ml = (float2*)alloc(32768ull * 8);     // (4,128,64)
    float* affb  = (float*)alloc(196608ull * 4);
    u16*  o16 = (u16*)alloc(524288ull * 2);
    float* oproj = (float*)alloc(524288ull * 4);
    float* xb    = (float*)alloc(524288ull * 4);
    u16*  x16 = (u16*)alloc(524288ull * 2);
    u16*  h116 = (u16*)alloc(2097152ull * 2);
    float* ffb   = (float*)alloc(524288ull * 4);
    float* uvec  = (float*)alloc(24576ull * 4);
    float* cb    = (float*)alloc(48ull * 4);
    float* part2 = (float*)VT16;                   // alias: VT dead after flash

    float* out_f = (float*)d_out;
    float* outs_base  = out_f;                     // (3,16,64,512)
    float* attns_base = out_f + 1572864;           // (3,16,64,4096)
    float* affs_base  = out_f + 14155776;          // (3,16,1,1,4096)

    // prep (layer-independent)
    umat_k<<<dim3(3, 128), 256, 0, stream>>>(Wk, extra, uvec);
    cbk_k<<<12, 256, 0, stream>>>(bk, extra, cb);
    cvt16_aff_k<<<16384, 256, 0, stream>>>(feat, feat16, uvec, cb, affb, affs_base);
    initx_k<<<256, 256, 0, stream>>>(queries, xb, x16);
    transpose_w_k<<<dim3(16, 16, 3), 256, 0, stream>>>(Wq, WqT, 512, 512);
    transpose_w_k<<<dim3(16, 16, 3), 256, 0, stream>>>(Wk, WkT, 512, 512);
    transpose_w_k<<<dim3(16, 16, 3), 256, 0, stream>>>(Wv, WvT, 512, 512);
    transpose_w_k<<<dim3(16, 16, 3), 256, 0, stream>>>(Wo, WoT, 512, 512);
    transpose_w_k<<<dim3(64, 16, 3), 256, 0, stream>>>(W1, W1T, 512, 2048);
    transpose_w_k<<<dim3(16, 64, 3), 256, 0, stream>>>(W2, W2T, 2048, 512);

    for (int i = 0; i < 3; ++i) {
        // K = feat @ Wk + bk -> bf16 (B,Nk,C)
        gemm256v2_k<false, true, false><<<dim3(2, 256, 1), 512, 0, stream>>>(
            feat16, WkT + i * 262144, bk + i * 512, K16,
            512, 512, 512, 0, 0, 0, nullptr);
        // VT' = aff ⊙ ((feat @ Wv)^T + bv) -> (B,C,Nk)
        gemm256v2_k<true, true, true><<<dim3(16, 2, 16), 512, 0, stream>>>(
            WvT + i * 262144, feat16, bv + i * 512, VT16,
            512, 512, 4096, 0, 2097152, 2097152, affb + i * 65536);
        // q = x @ Wq + bq (raw)
        gemm_bt_k<64, 64, true, false, false, true>
            <<<dim3(8, 16, 1), 256, 0, stream>>>(
            x16, WqT + i * 262144, bq + i * 512, q16,
            512, 512, 512, 512, 0, 0, 0, 1.f);
        // attns[b] = (SCALE/8) q[b] @ K[b]^T -> fp32 (16,64,4096)
        gemm_bt_k<64, 128, false, false, false, false>
            <<<dim3(32, 1, 16), 256, 0, stream>>>(
            q16, K16, nullptr, attns_base + (size_t)i * 4194304,
            512, 512, 512, 4096, 32768, 2097152, 262144, 0.015625f);
        // flash attention (4 kv-splits) + merge -> o16
        fattn_k<<<dim3(4, 128), 256, 0, stream>>>(q16, K16, VT16, Op, ml);
        fmerge_k<<<512, 256, 0, stream>>>(Op, ml, o16);
        // o @ Wo + bo -> fp32
        gemm_bt_k<64, 64, false, false, false, true>
            <<<dim3(8, 16, 1), 256, 0, stream>>>(
            o16, WoT + i * 262144, bo + i * 512, oproj,
            512, 512, 512, 512, 0, 0, 0, 1.f);
        // x = LN(x + oproj; g2, beta2)
        ln_k<false><<<1024, 256, 0, stream>>>(xb, oproj, g2 + i * 512, be2 + i * 512, x16, nullptr);
        // h1 = relu(x @ W1 + b1) -> bf16
        gemm_bt_k<64, 128, true, true, false, true>
            <<<dim3(16, 16, 1), 256, 0, stream>>>(
            x16, W1T + (size_t)i * 1048576, b1 + i * 2048, h116,
            512, 512, 512, 2048, 0, 0, 0, 1.f);
        // ff partials = h1 @ W2 (split-K 4)
        gemm_bt_k<64, 64, false, false, false, false>
            <<<dim3(8, 16, 4), 256, 0, stream>>>(
            h116, W2T + (size_t)i * 1048576, nullptr, part2,
            512, 2048, 2048, 512, 512, 512, 524288, 1.f);
        ffred_k<<<512, 256, 0, stream>>>(part2, b2 + i * 512, ffb);
        // x = LN(x + ff; g3, beta3), write outs[i]
        ln_k<true><<<1024, 256, 0, stream>>>(xb, ffb, g3 + i * 512, be3 + i * 512, x16,
                                             outs_base + (size_t)i * 524288);
    }
}

// Round 12
// 658.015 us; speedup vs baseline: 1.0466x; 1.0035x over previous
//
#include <hip/hip_runtime.h>

// SegDecoder: 3-layer cross-attention decoder on MI355X (gfx950).
// B=16, Nq=64, Nk=4096, C=512, H=8, hd=64, FF=2048, L=3.
// R12: big-GEMM v3 = R11's K-half ring + counted vmcnt, PLUS register
// fragment prefetch (read next phase's frags before MFMA on current regs —
// m201's key pipeline piece R11 lacked). All else identical to R11.

typedef unsigned short u16;
typedef __attribute__((ext_vector_type(8))) short short8;
typedef __attribute__((ext_vector_type(4))) short short4v;
typedef __attribute__((ext_vector_type(4))) float f32x4;

__device__ __forceinline__ float b2f(u16 u) {
    union { unsigned int i; float f; } v; v.i = ((unsigned int)u) << 16; return v.f;
}
__device__ __forceinline__ u16 f2b(float f) {  // round-to-nearest-even
    unsigned int x = __float_as_uint(f);
    x += 0x7fffu + ((x >> 16) & 1u);
    return (u16)(x >> 16);
}

__device__ __forceinline__ float waveSum(float v) {
#pragma unroll
    for (int o = 32; o > 0; o >>= 1) v += __shfl_xor(v, o);
    return v;
}

// async global->LDS, 16B per lane. LDS dest is wave-uniform base + lane*16.
__device__ __forceinline__ void gl_lds16(const void* g, void* l) {
    __builtin_amdgcn_global_load_lds(
        (__attribute__((address_space(1))) void*)g,
        (__attribute__((address_space(3))) void*)l, 16, 0, 0);
}

// ---------------------------------------------------------------------------
// Big-GEMM v3 (Kproj / VT): BM=BN=256, 8 waves (2M x 4N), per-wave C=128x64.
// K split into 16 K-halves of 32 cols; 4-slot LDS ring (128KB, 1 block/CU).
// Per K-half h, 2 phases with REGISTER FRAG PREFETCH:
//   p0: stage 2 rounds (h+3) ; ds_read afB (h frags 4-7) ; MFMA afA x bfC
//   p1: stage 2 rounds (h+3) ; counted vmcnt+barrier (h+1 landed) ;
//       ds_read bfC',afA' (h+1) ; MFMA afB x bfC ; swap
// MFMA never depends on a same-phase ds_read. Waits: vmcnt(8) steady,
// 4/0 tail (per-wave own-loads; barrier joins waves). XCD-chunk swizzle.
// ---------------------------------------------------------------------------
template<bool BIAS_ROW, bool HAS_BIAS, bool AFFC>
__global__ __launch_bounds__(512, 1) void gemm256v3_k(
    const u16* __restrict__ A, const u16* __restrict__ Bt,
    const float* __restrict__ bias, u16* __restrict__ Cout,
    int lda, int ldb, int ldc, long sA2, long sB2, long sC2,
    const float* __restrict__ affc)
{
    __shared__ u16 Ah[4][256][32];   // 64 KB
    __shared__ u16 Bh[4][256][32];   // 64 KB
    const int tid = threadIdx.x;
    const int lane = tid & 63;
    const int wave = tid >> 6;        // 0..7

    // bijective XCD-chunk swizzle (m204)
    const int gx = gridDim.x, gy = gridDim.y;
    const int nwg = gx * gy * gridDim.z;
    int id;
    {
        const int orig = blockIdx.x + blockIdx.y * gx + blockIdx.z * gx * gy;
        const int qq = nwg >> 3, rr = nwg & 7;
        const int xcd = orig & 7, sub = orig >> 3;
        id = (xcd < rr ? xcd * (qq + 1) : rr * (qq + 1) + (xcd - rr) * qq) + sub;
    }
    const int bx = id % gx;
    const int by = (id / gx) % gy;
    const int z  = id / (gx * gy);

    A  += (long)z * sA2;
    Bt += (long)z * sB2;
    const long cbase = (long)z * sC2;
    const int n0 = bx * 256;
    const int m0 = by * 256;
    const int wm = wave >> 2;         // 0..1 (128-row A slab)
    const int wn = wave & 3;          // 0..3 (64-row B slab)
    const int rl = lane & 15;
    const int uq = lane >> 4;         // 16B unit within 32-col row
    const int srow = lane >> 2;       // 0..15
    const int up   = lane & 3;

    f32x4 acc[8][4];
#pragma unroll
    for (int i = 0; i < 8; ++i)
#pragma unroll
        for (int j = 0; j < 4; ++j) acc[i][j] = (f32x4){0.f, 0.f, 0.f, 0.f};

    // one round = 1KB = 16 rows x 64B; K-half h = 4 rounds/wave (2 A + 2 B)
    auto stage_round = [&](int h, int r) {
        const int slot = h & 3;
        const int k0 = h * 32;
        if (r < 2) {
            const int row = r * 128 + wave * 16 + srow;
            const int ul = up ^ ((row >> 2) & 3);
            gl_lds16(A + (long)(m0 + row) * lda + k0 + ul * 8,
                     &Ah[slot][r * 128 + wave * 16][0]);
        } else {
            const int row = (r - 2) * 128 + wave * 16 + srow;
            const int ul = up ^ ((row >> 2) & 3);
            gl_lds16(Bt + (long)(n0 + row) * ldb + k0 + ul * 8,
                     &Bh[slot][(r - 2) * 128 + wave * 16][0]);
        }
    };
    auto read_af = [&](int slot, int base, short8* dst) {
#pragma unroll
        for (int i = 0; i < 4; ++i) {
            const int R = wm * 128 + (base + i) * 16 + rl;
            dst[i] = *(const short8*)(&Ah[slot][R][(uq ^ ((R >> 2) & 3)) * 8]);
        }
    };
    auto read_bf = [&](int slot, short8* dst) {
#pragma unroll
        for (int j = 0; j < 4; ++j) {
            const int R = wn * 64 + j * 16 + rl;
            dst[j] = *(const short8*)(&Bh[slot][R][(uq ^ ((R >> 2) & 3)) * 8]);
        }
    };

    // prologue: stage K-halves 0,1,2 (12 rounds); drain oldest 4 (h0 ready)
#pragma unroll
    for (int h = 0; h < 3; ++h)
#pragma unroll
        for (int r = 0; r < 4; ++r) stage_round(h, r);
    asm volatile("s_waitcnt vmcnt(8)\n\ts_barrier" ::: "memory");

    short8 afA[4], afB[4], bfC[4], afN[4], bfN[4];
    read_bf(0, bfC);
    read_af(0, 0, afA);

#pragma unroll
    for (int h = 0; h < 16; ++h) {
        const int slot = h & 3;
        // ---- p0: MFMA on afA x bfC (already in regs); read afB(h) ----
        if (h + 3 < 16) { stage_round(h + 3, 0); stage_round(h + 3, 1); }
        read_af(slot, 4, afB);
        __builtin_amdgcn_s_setprio(1);
#pragma unroll
        for (int i = 0; i < 4; ++i)
#pragma unroll
            for (int j = 0; j < 4; ++j)
                acc[i][j] = __builtin_amdgcn_mfma_f32_16x16x32_bf16(
                    afA[i], bfC[j], acc[i][j], 0, 0, 0);
        __builtin_amdgcn_s_setprio(0);

        // ---- p1: wait h+1 landed; read h+1 frags; MFMA on afB x bfC ----
        if (h + 3 < 16) { stage_round(h + 3, 2); stage_round(h + 3, 3); }
        if (h < 13)
            asm volatile("s_waitcnt vmcnt(8)\n\ts_barrier" ::: "memory");
        else if (h == 13)
            asm volatile("s_waitcnt vmcnt(4)\n\ts_barrier" ::: "memory");
        else if (h == 14)
            asm volatile("s_waitcnt vmcnt(0)\n\ts_barrier" ::: "memory");
        if (h < 15) {
            read_bf((h + 1) & 3, bfN);
            read_af((h + 1) & 3, 0, afN);
        }
        __builtin_amdgcn_s_setprio(1);
#pragma unroll
        for (int i = 0; i < 4; ++i)
#pragma unroll
            for (int j = 0; j < 4; ++j)
                acc[4 + i][j] = __builtin_amdgcn_mfma_f32_16x16x32_bf16(
                    afB[i], bfC[j], acc[4 + i][j], 0, 0, 0);
        __builtin_amdgcn_s_setprio(0);
        if (h < 15) {
#pragma unroll
            for (int i = 0; i < 4; ++i) { afA[i] = afN[i]; bfC[i] = bfN[i]; }
        }
    }

    const int r0 = (lane >> 4) * 4;
    const int c0 = lane & 15;
#pragma unroll
    for (int i = 0; i < 8; ++i) {
#pragma unroll
        for (int j = 0; j < 4; ++j) {
#pragma unroll
            for (int r = 0; r < 4; ++r) {
                const int row = m0 + wm * 128 + i * 16 + r0 + r;
                const int col = n0 + wn * 64 + j * 16 + c0;
                float v = acc[i][j][r];
                if constexpr (HAS_BIAS) {
                    if constexpr (BIAS_ROW) v += bias[row]; else v += bias[col];
                }
                if constexpr (AFFC) v *= affc[(long)z * 4096 + col];
                Cout[cbase + (long)row * ldc + col] = f2b(v);
            }
        }
    }
}

// ---------------------------------------------------------------------------
// Flash attention partial (R9, proven): block = (split, bh).
// ---------------------------------------------------------------------------
__global__ __launch_bounds__(256) void fattn_k(
    const u16* __restrict__ q16, const u16* __restrict__ K16,
    const u16* __restrict__ VT16, float* __restrict__ Op,
    float2* __restrict__ ml)
{
    __shared__ u16 Qs[64][64];
    __shared__ u16 Ks[128][64];
    __shared__ u16 Vs[64][128];
    __shared__ u16 Ps[64][128];
    const int t = threadIdx.x;
    const int lane = t & 63;
    const int w = t >> 6;
    const int bh = blockIdx.y;
    const int split = blockIdx.x;
    const int b = bh >> 3, h = bh & 7;
    const int kbase = split * 1024;
    const int rl = lane & 15, uq = lane >> 4;
    const int r0 = (lane >> 4) * 4;
    const int c0 = lane & 15;
    const int srow8 = lane >> 3, up8 = lane & 7;
    const int srow4 = lane >> 4, up16 = lane & 15;

#pragma unroll
    for (int rnd = 0; rnd < 2; ++rnd) {
        const int row = rnd * 32 + w * 8 + srow8;
        const int ul = up8 ^ (row & 7);
        gl_lds16(q16 + ((long)(b * 64 + row)) * 512 + h * 64 + ul * 8,
                 &Qs[rnd * 32 + w * 8][0]);
    }

    f32x4 O[4];
#pragma unroll
    for (int n = 0; n < 4; ++n) O[n] = (f32x4){0.f, 0.f, 0.f, 0.f};
    float m_run[4] = {-3.0e38f, -3.0e38f, -3.0e38f, -3.0e38f};
    float l_run[4] = {0.f, 0.f, 0.f, 0.f};

    const int R = w * 16 + rl;

    for (int tt = 0; tt < 8; ++tt) {
        __syncthreads();
#pragma unroll
        for (int rnd = 0; rnd < 4; ++rnd) {
            const int row = rnd * 32 + w * 8 + srow8;
            const int ul = up8 ^ (row & 7);
            gl_lds16(K16 + ((long)(b * 4096 + kbase + tt * 128 + row)) * 512
                         + h * 64 + ul * 8,
                     &Ks[rnd * 32 + w * 8][0]);
        }
#pragma unroll
        for (int rnd = 0; rnd < 4; ++rnd) {
            const int row = rnd * 16 + w * 4 + srow4;
            const int ul = up16 ^ (row & 15);
            gl_lds16(VT16 + (long)b * 2097152 + ((long)(h * 64 + row)) * 4096
                         + kbase + tt * 128 + ul * 8,
                     &Vs[rnd * 16 + w * 4][0]);
        }
        __syncthreads();

        f32x4 s[8];
        short8 af[2];
#pragma unroll
        for (int kc = 0; kc < 2; ++kc)
            af[kc] = *(const short8*)(&Qs[R][((kc * 4 + uq) ^ (R & 7)) * 8]);
#pragma unroll
        for (int j = 0; j < 8; ++j) {
            s[j] = (f32x4){0.f, 0.f, 0.f, 0.f};
            const int Rb = j * 16 + rl;
#pragma unroll
            for (int kc = 0; kc < 2; ++kc) {
                short8 bf = *(const short8*)(&Ks[Rb][((kc * 4 + uq) ^ (Rb & 7)) * 8]);
                s[j] = __builtin_amdgcn_mfma_f32_16x16x32_bf16(af[kc], bf, s[j], 0, 0, 0);
            }
        }
#pragma unroll
        for (int j = 0; j < 8; ++j)
#pragma unroll
            for (int r = 0; r < 4; ++r) s[j][r] *= 0.125f;

        float mv[4];
#pragma unroll
        for (int r = 0; r < 4; ++r) {
            float m = s[0][r];
#pragma unroll
            for (int j = 1; j < 8; ++j) m = fmaxf(m, s[j][r]);
#pragma unroll
            for (int mask = 1; mask < 16; mask <<= 1)
                m = fmaxf(m, __shfl_xor(m, mask));
            mv[r] = m;
        }
        float al[4], rs[4];
#pragma unroll
        for (int r = 0; r < 4; ++r) {
            const float mn = fmaxf(m_run[r], mv[r]);
            al[r] = __expf(m_run[r] - mn);
            m_run[r] = mn;
            rs[r] = 0.f;
        }
#pragma unroll
        for (int j = 0; j < 8; ++j)
#pragma unroll
            for (int r = 0; r < 4; ++r) {
                s[j][r] = __expf(s[j][r] - m_run[r]);
                rs[r] += s[j][r];
            }
#pragma unroll
        for (int r = 0; r < 4; ++r) {
#pragma unroll
            for (int mask = 1; mask < 16; mask <<= 1)
                rs[r] += __shfl_xor(rs[r], mask);
            l_run[r] = l_run[r] * al[r] + rs[r];
        }
#pragma unroll
        for (int n = 0; n < 4; ++n)
#pragma unroll
            for (int r = 0; r < 4; ++r) O[n][r] *= al[r];

#pragma unroll
        for (int j = 0; j < 8; ++j)
#pragma unroll
            for (int r = 0; r < 4; ++r) {
                const int row = w * 16 + r0 + r;
                const int col = j * 16 + c0;
                Ps[row][(((col >> 3) ^ (row & 15)) << 3) + (col & 7)] = f2b(s[j][r]);
            }
#pragma unroll
        for (int kc4 = 0; kc4 < 4; ++kc4) {
            const short8 afp = *(const short8*)(&Ps[R][(((kc4 * 4 + uq) ^ (R & 15)) << 3)]);
#pragma unroll
            for (int n = 0; n < 4; ++n) {
                const int Rv = n * 16 + rl;
                const short8 bfv = *(const short8*)(&Vs[Rv][(((kc4 * 4 + uq) ^ (Rv & 15)) << 3)]);
                O[n] = __builtin_amdgcn_mfma_f32_16x16x32_bf16(afp, bfv, O[n], 0, 0, 0);
            }
        }
    }

    const long obase = ((long)(split * 128 + bh)) * 64;
#pragma unroll
    for (int n = 0; n < 4; ++n)
#pragma unroll
        for (int r = 0; r < 4; ++r) {
            const int q = w * 16 + r0 + r;
            Op[(obase + q) * 64 + n * 16 + c0] = O[n][r];
        }
    if (c0 == 0) {
#pragma unroll
        for (int r = 0; r < 4; ++r) {
            const int q = w * 16 + r0 + r;
            ml[obase + q] = make_float2(m_run[r], l_run[r]);
        }
    }
}

// merge 4 flash splits -> o16 (B,Nq,C)
__global__ __launch_bounds__(256) void fmerge_k(
    const float* __restrict__ Op, const float2* __restrict__ ml,
    u16* __restrict__ o16)
{
    const int i = blockIdx.x * 256 + threadIdx.x;
    const int d4 = i & 15;
    const int q  = (i >> 4) & 63;
    const int bh = i >> 10;
    const float2 m0 = ml[((long)(0 * 128 + bh)) * 64 + q];
    const float2 m1 = ml[((long)(1 * 128 + bh)) * 64 + q];
    const float2 m2 = ml[((long)(2 * 128 + bh)) * 64 + q];
    const float2 m3 = ml[((long)(3 * 128 + bh)) * 64 + q];
    const float m = fmaxf(fmaxf(m0.x, m1.x), fmaxf(m2.x, m3.x));
    const float e0 = __expf(m0.x - m), e1 = __expf(m1.x - m);
    const float e2 = __expf(m2.x - m), e3 = __expf(m3.x - m);
    const float inv = 1.f / (m0.y * e0 + m1.y * e1 + m2.y * e2 + m3.y * e3);
    const float4 v0 = *(const float4*)(Op + (((long)(0 * 128 + bh)) * 64 + q) * 64 + d4 * 4);
    const float4 v1 = *(const float4*)(Op + (((long)(1 * 128 + bh)) * 64 + q) * 64 + d4 * 4);
    const float4 v2 = *(const float4*)(Op + (((long)(2 * 128 + bh)) * 64 + q) * 64 + d4 * 4);
    const float4 v3 = *(const float4*)(Op + (((long)(3 * 128 + bh)) * 64 + q) * 64 + d4 * 4);
    float4 acc;
    acc.x = (v0.x * e0 + v1.x * e1 + v2.x * e2 + v3.x * e3) * inv;
    acc.y = (v0.y * e0 + v1.y * e1 + v2.y * e2 + v3.y * e3) * inv;
    acc.z = (v0.z * e0 + v1.z * e1 + v2.z * e2 + v3.z * e3) * inv;
    acc.w = (v0.w * e0 + v1.w * e1 + v2.w * e2 + v3.w * e3) * inv;
    const int b = bh >> 3, h = bh & 7;
    short4v r;
    r[0] = (short)f2b(acc.x); r[1] = (short)f2b(acc.y);
    r[2] = (short)f2b(acc.z); r[3] = (short)f2b(acc.w);
    *(short4v*)(o16 + (long)b * 32768 + q * 512 + h * 64 + d4 * 4) = r;
}

// ---------------------------------------------------------------------------
// Generic batched GEMM: C = alpha*A@Bt^T [+bias][relu]; BK=64 single-buffered.
// ---------------------------------------------------------------------------
template<int TM, int TN, bool OUT_BF16, bool RELU, bool BIAS_ROW, bool HAS_BIAS>
__global__ __launch_bounds__(256) void gemm_bt_k(
    const u16* __restrict__ A, const u16* __restrict__ Bt,
    const float* __restrict__ bias, void* __restrict__ Cout,
    int K, int lda, int ldb, int ldc,
    long sA1, long sB1, long sC1, float alpha)
{
    __shared__ u16 As[TM][64];
    __shared__ u16 Bs[TN][64];
    const int t = threadIdx.x;
    const int lane = t & 63;
    const int wave = t >> 6;
    const int z = blockIdx.z;
    A  += (long)z * sA1;
    Bt += (long)z * sB1;
    const long cbase = (long)z * sC1;
    const int n0 = blockIdx.x * TN;
    const int m0 = blockIdx.y * TM;
    constexpr int FM = TM / 32, FN = TN / 32;
    const int wr = wave >> 1, wc = wave & 1;
    const int rl = lane & 15, uq = lane >> 4;

    f32x4 acc[FM][FN];
#pragma unroll
    for (int i = 0; i < FM; ++i)
#pragma unroll
        for (int j = 0; j < FN; ++j) acc[i][j] = (f32x4){0.f, 0.f, 0.f, 0.f};

    const int srow = lane >> 3;
    const int up   = lane & 7;

    for (int k0 = 0; k0 < K; k0 += 64) {
        __syncthreads();
#pragma unroll
        for (int r = 0; r < TM / 32; ++r) {
            const int br = (wave * (TM / 32) + r) * 8;
            const int row = br + srow;
            const int ul = up ^ (row & 7);
            gl_lds16(A + (long)(m0 + row) * lda + k0 + ul * 8, &As[br][0]);
        }
#pragma unroll
        for (int r = 0; r < TN / 32; ++r) {
            const int br = (wave * (TN / 32) + r) * 8;
            const int row = br + srow;
            const int ul = up ^ (row & 7);
            gl_lds16(Bt + (long)(n0 + row) * ldb + k0 + ul * 8, &Bs[br][0]);
        }
        __syncthreads();

#pragma unroll
        for (int kc = 0; kc < 2; ++kc) {
            short8 af[FM], bf[FN];
#pragma unroll
            for (int i = 0; i < FM; ++i) {
                const int R = wr * (TM / 2) + i * 16 + rl;
                af[i] = *(const short8*)(&As[R][((kc * 4 + uq) ^ (R & 7)) * 8]);
            }
#pragma unroll
            for (int j = 0; j < FN; ++j) {
                const int R = wc * (TN / 2) + j * 16 + rl;
                bf[j] = *(const short8*)(&Bs[R][((kc * 4 + uq) ^ (R & 7)) * 8]);
            }
#pragma unroll
            for (int i = 0; i < FM; ++i)
#pragma unroll
                for (int j = 0; j < FN; ++j)
                    acc[i][j] = __builtin_amdgcn_mfma_f32_16x16x32_bf16(
                        af[i], bf[j], acc[i][j], 0, 0, 0);
        }
    }

    const int r0 = (lane >> 4) * 4;
    const int c0 = lane & 15;
#pragma unroll
    for (int i = 0; i < FM; ++i) {
#pragma unroll
        for (int j = 0; j < FN; ++j) {
#pragma unroll
            for (int r = 0; r < 4; ++r) {
                const int row = m0 + wr * (TM / 2) + i * 16 + r0 + r;
                const int col = n0 + wc * (TN / 2) + j * 16 + c0;
                float v = acc[i][j][r] * alpha;
                if constexpr (HAS_BIAS) {
                    if constexpr (BIAS_ROW) v += bias[row]; else v += bias[col];
                }
                if constexpr (RELU) v = fmaxf(v, 0.f);
                const long idx = cbase + (long)row * ldc + col;
                if constexpr (OUT_BF16) ((u16*)Cout)[idx] = f2b(v);
                else                    ((float*)Cout)[idx] = v;
            }
        }
    }
}

// split-K FF2 reduce + bias
__global__ __launch_bounds__(256) void ffred_k(
    const float* __restrict__ part, const float* __restrict__ bias,
    float* __restrict__ out)
{
    const int i = (blockIdx.x * 256 + threadIdx.x) * 4;
    const int c = i & 511;
    float4 s = *(const float4*)(part + i);
#pragma unroll
    for (int sp = 1; sp < 4; ++sp) {
        const float4 v = *(const float4*)(part + (long)sp * 524288 + i);
        s.x += v.x; s.y += v.y; s.z += v.z; s.w += v.w;
    }
    s.x += bias[c]; s.y += bias[c + 1]; s.z += bias[c + 2]; s.w += bias[c + 3];
    *(float4*)(out + i) = s;
}

// u[l][b][c'] = sum_c Wk[l][c'][c] * extra[b][c]
__global__ __launch_bounds__(256) void umat_k(
    const float* __restrict__ Wk, const float* __restrict__ extra,
    float* __restrict__ u)
{
    __shared__ float ex[16][512];
    const int l = blockIdx.x;
    const int t = threadIdx.x;
    for (int i = t; i < 16 * 512 / 4; i += 256)
        ((float4*)&ex[0][0])[i] = ((const float4*)extra)[i];
    __syncthreads();
    const int lane = t & 63, wave = t >> 6;
    const int row = blockIdx.y * 4 + wave;
    const float* wrow = Wk + ((size_t)l * 512 + row) * 512 + lane * 8;
    float w[8];
#pragma unroll
    for (int j = 0; j < 8; ++j) w[j] = wrow[j];
    float s[16];
#pragma unroll
    for (int b = 0; b < 16; ++b) {
        float x = 0.f;
#pragma unroll
        for (int j = 0; j < 8; ++j) x += w[j] * ex[b][lane * 8 + j];
        s[b] = waveSum(x);
    }
    if (lane < 16) u[((size_t)l * 16 + lane) * 512 + row] = s[lane];
}

// cb[l*16+b] = dot(extra[b], bk[l])
__global__ __launch_bounds__(256) void cbk_k(
    const float* __restrict__ bk, const float* __restrict__ extra,
    float* __restrict__ cb)
{
    const int gw = blockIdx.x * 4 + (threadIdx.x >> 6);
    const int lane = threadIdx.x & 63;
    const int l = gw >> 4, b = gw & 15;
    float s = 0.f;
#pragma unroll
    for (int j = 0; j < 8; ++j)
        s += extra[b * 512 + lane * 8 + j] * bk[l * 512 + lane * 8 + j];
    s = waveSum(s);
    if (lane == 0) cb[gw] = s;
}

// feat fp32 -> bf16, fused with aff for all 3 layers
__global__ __launch_bounds__(256) void cvt16_aff_k(
    const float* __restrict__ feat, u16* __restrict__ dst,
    const float* __restrict__ u, const float* __restrict__ cb,
    float* __restrict__ affb, float* __restrict__ affs_out)
{
    const int t = blockIdx.x * 256 + threadIdx.x;
    const long i = (long)t * 8;
    const int lane = threadIdx.x & 63;
    const int r = t >> 6;
    const int b = r >> 12;
    const float4 a0 = *(const float4*)(feat + i);
    const float4 a1 = *(const float4*)(feat + i + 4);
    short8 o;
    o[0] = (short)f2b(a0.x); o[1] = (short)f2b(a0.y);
    o[2] = (short)f2b(a0.z); o[3] = (short)f2b(a0.w);
    o[4] = (short)f2b(a1.x); o[5] = (short)f2b(a1.y);
    o[6] = (short)f2b(a1.z); o[7] = (short)f2b(a1.w);
    *(short8*)(dst + i) = o;
    const float f[8] = {a0.x, a0.y, a0.z, a0.w, a1.x, a1.y, a1.z, a1.w};
#pragma unroll
    for (int l = 0; l < 3; ++l) {
        const float* ur = u + ((size_t)l * 16 + b) * 512 + lane * 8;
        float s = 0.f;
#pragma unroll
        for (int j = 0; j < 8; ++j) s += f[j] * ur[j];
        s = waveSum(s);
        if (lane == 0) {
            const float av = 1.f / (1.f + __expf(-0.015625f * (s + cb[l * 16 + b])));
            affb[l * 65536 + r] = av;
            affs_out[l * 65536 + r] = av;
        }
    }
}

// x = LN(x + add; g, beta)
template<bool WRITE_OUT>
__global__ __launch_bounds__(256) void ln_k(
    float* __restrict__ x, const float* __restrict__ add,
    const float* __restrict__ g, const float* __restrict__ be,
    u16* __restrict__ x16, float* __restrict__ outp)
{
    const int r = blockIdx.x, t = threadIdx.x;
    const int w = t >> 6, lane = t & 63;
    __shared__ float red[4];
    float* xr = x + (long)r * 512;
    const float* ar = add + (long)r * 512;
    const float v0 = xr[2 * t]     + ar[2 * t];
    const float v1 = xr[2 * t + 1] + ar[2 * t + 1];
    float s = waveSum(v0 + v1);
    if (lane == 0) red[w] = s;
    __syncthreads();
    s = red[0] + red[1] + red[2] + red[3];
    const float mu = s * (1.f / 512.f);
    const float d0 = v0 - mu, d1 = v1 - mu;
    __syncthreads();
    float vs = waveSum(d0 * d0 + d1 * d1);
    if (lane == 0) red[w] = vs;
    __syncthreads();
    vs = red[0] + red[1] + red[2] + red[3];
    const float rs = rsqrtf(vs * (1.f / 512.f) + 1e-5f);
    const float o0 = g[2 * t]     * d0 * rs + be[2 * t];
    const float o1 = g[2 * t + 1] * d1 * rs + be[2 * t + 1];
    xr[2 * t] = o0; xr[2 * t + 1] = o1;
    x16[(long)r * 512 + 2 * t]     = f2b(o0);
    x16[(long)r * 512 + 2 * t + 1] = f2b(o1);
    if constexpr (WRITE_OUT) {
        outp[(long)r * 512 + 2 * t]     = o0;
        outp[(long)r * 512 + 2 * t + 1] = o1;
    }
}

// x = copy(queries) fp32 + bf16
__global__ __launch_bounds__(256) void initx_k(
    const float* __restrict__ src, float* __restrict__ x, u16* __restrict__ x16)
{
    const long i = ((long)blockIdx.x * 256 + threadIdx.x) * 8;
    const float4 a = *(const float4*)(src + i);
    const float4 b = *(const float4*)(src + i + 4);
    *(float4*)(x + i) = a;
    *(float4*)(x + i + 4) = b;
    short8 r;
    r[0] = (short)f2b(a.x); r[1] = (short)f2b(a.y); r[2] = (short)f2b(a.z); r[3] = (short)f2b(a.w);
    r[4] = (short)f2b(b.x); r[5] = (short)f2b(b.y); r[6] = (short)f2b(b.z); r[7] = (short)f2b(b.w);
    *(short8*)(x16 + i) = r;
}

// W (K,N) fp32 -> WT (N,K) bf16, batched over blockIdx.z
__global__ __launch_bounds__(256) void transpose_w_k(
    const float* __restrict__ W, u16* __restrict__ WT, int K, int N)
{
    __shared__ float tile[32][33];
    const int z = blockIdx.z;
    W  += (size_t)z * K * N;
    WT += (size_t)z * K * N;
    const int n0 = blockIdx.x * 32, k0 = blockIdx.y * 32;
    const int tx = threadIdx.x & 31, ty = threadIdx.x >> 5;
#pragma unroll
    for (int j = 0; j < 32; j += 8)
        tile[ty + j][tx] = W[(size_t)(k0 + ty + j) * N + n0 + tx];
    __syncthreads();
#pragma unroll
    for (int j = 0; j < 32; j += 8)
        WT[(size_t)(n0 + ty + j) * K + k0 + tx] = f2b(tile[tx][ty + j]);
}

// ---------------------------------------------------------------------------
extern "C" void kernel_launch(void* const* d_in, const int* in_sizes, int n_in,
                              void* d_out, int out_size, void* d_ws, size_t ws_size,
                              hipStream_t stream)
{
    (void)in_sizes; (void)n_in; (void)out_size; (void)ws_size;
    const float* queries = (const float*)d_in[0];
    const float* feat    = (const float*)d_in[1];
    const float* extra   = (const float*)d_in[2];
    const float* Wq = (const float*)d_in[3];  const float* bq = (const float*)d_in[4];
    const float* Wk = (const float*)d_in[5];  const float* bk = (const float*)d_in[6];
    const float* Wv = (const float*)d_in[7];  const float* bv = (const float*)d_in[8];
    const float* Wo = (const float*)d_in[9];  const float* bo = (const float*)d_in[10];
    const float* W1 = (const float*)d_in[11]; const float* b1 = (const float*)d_in[12];
    const float* W2 = (const float*)d_in[13]; const float* b2 = (const float*)d_in[14];
    const float* g2 = (const float*)d_in[15]; const float* be2 = (const float*)d_in[16];
    const float* g3 = (const float*)d_in[17]; const float* be3 = (const float*)d_in[18];

    char* wsb = (char*)d_ws;
    size_t off = 0;
    auto alloc = [&](size_t bytes) -> char* {
        char* p = wsb + off; off += (bytes + 255) & ~(size_t)255; return p;
    };
    u16*  feat16 = (u16*)alloc(33554432ull * 2);   // (B*Nk, C) bf16
    u16*  WqT = (u16*)alloc(786432ull * 2);
    u16*  WkT = (u16*)alloc(786432ull * 2);
    u16*  WvT = (u16*)alloc(786432ull * 2);
    u16*  WoT = (u16*)alloc(786432ull * 2);
    u16*  W1T = (u16*)alloc(3145728ull * 2);
    u16*  W2T = (u16*)alloc(3145728ull * 2);
    u16*  K16 = (u16*)alloc(33554432ull * 2);      // (B,Nk,C)
    u16*  VT16 = (u16*)alloc(33554432ull * 2);     // (B,C,Nk); later FF2 partials
    u16*  q16 = (u16*)alloc(524288ull * 2);        // (B*Nq, C)
    float* Op  = (float*)alloc(4194304ull * 4);    // flash partials (4,128,64,64)
    float2* ml = (float2*)alloc(32768ull * 8);     // (4,128,64)
    float* affb  = (float*)alloc(196608ull * 4);
    u16*  o16 = (u16*)alloc(524288ull * 2);
    float* oproj = (float*)alloc(524288ull * 4);
    float* xb    = (float*)alloc(524288ull * 4);
    u16*  x16 = (u16*)alloc(524288ull * 2);
    u16*  h116 = (u16*)alloc(2097152ull * 2);
    float* ffb   = (float*)alloc(524288ull * 4);
    float* uvec  = (float*)alloc(24576ull * 4);
    float* cb    = (float*)alloc(48ull * 4);
    float* part2 = (float*)VT16;                   // alias: VT dead after flash

    float* out_f = (float*)d_out;
    float* outs_base  = out_f;                     // (3,16,64,512)
    float* attns_base = out_f + 1572864;           // (3,16,64,4096)
    float* affs_base  = out_f + 14155776;          // (3,16,1,1,4096)

    // prep (layer-independent)
    umat_k<<<dim3(3, 128), 256, 0, stream>>>(Wk, extra, uvec);
    cbk_k<<<12, 256, 0, stream>>>(bk, extra, cb);
    cvt16_aff_k<<<16384, 256, 0, stream>>>(feat, feat16, uvec, cb, affb, affs_base);
    initx_k<<<256, 256, 0, stream>>>(queries, xb, x16);
    transpose_w_k<<<dim3(16, 16, 3), 256, 0, stream>>>(Wq, WqT, 512, 512);
    transpose_w_k<<<dim3(16, 16, 3), 256, 0, stream>>>(Wk, WkT, 512, 512);
    transpose_w_k<<<dim3(16, 16, 3), 256, 0, stream>>>(Wv, WvT, 512, 512);
    transpose_w_k<<<dim3(16, 16, 3), 256, 0, stream>>>(Wo, WoT, 512, 512);
    transpose_w_k<<<dim3(64, 16, 3), 256, 0, stream>>>(W1, W1T, 512, 2048);
    transpose_w_k<<<dim3(16, 64, 3), 256, 0, stream>>>(W2, W2T, 2048, 512);

    for (int i = 0; i < 3; ++i) {
        // K = feat @ Wk + bk -> bf16 (B,Nk,C)
        gemm256v3_k<false, true, false><<<dim3(2, 256, 1), 512, 0, stream>>>(
            feat16, WkT + i * 262144, bk + i * 512, K16,
            512, 512, 512, 0, 0, 0, nullptr);
        // VT' = aff ⊙ ((feat @ Wv)^T + bv) -> (B,C,Nk)
        gemm256v3_k<true, true, true><<<dim3(16, 2, 16), 512, 0, stream>>>(
            WvT + i * 262144, feat16, bv + i * 512, VT16,
            512, 512, 4096, 0, 2097152, 2097152, affb + i * 65536);
        // q = x @ Wq + bq (raw)
        gemm_bt_k<64, 64, true, false, false, true>
            <<<dim3(8, 16, 1), 256, 0, stream>>>(
            x16, WqT + i * 262144, bq + i * 512, q16,
            512, 512, 512, 512, 0, 0, 0, 1.f);
        // attns[b] = (SCALE/8) q[b] @ K[b]^T -> fp32 (16,64,4096)
        gemm_bt_k<64, 128, false, false, false, false>
            <<<dim3(32, 1, 16), 256, 0, stream>>>(
            q16, K16, nullptr, attns_base + (size_t)i * 4194304,
            512, 512, 512, 4096, 32768, 2097152, 262144, 0.015625f);
        // flash attention (4 kv-splits) + merge -> o16
        fattn_k<<<dim3(4, 128), 256, 0, stream>>>(q16, K16, VT16, Op, ml);
        fmerge_k<<<512, 256, 0, stream>>>(Op, ml, o16);
        // o @ Wo + bo -> fp32
        gemm_bt_k<64, 64, false, false, false, true>
            <<<dim3(8, 16, 1), 256, 0, stream>>>(
            o16, WoT + i * 262144, bo + i * 512, oproj,
            512, 512, 512, 512, 0, 0, 0, 1.f);
        // x = LN(x + oproj; g2, beta2)
        ln_k<false><<<1024, 256, 0, stream>>>(xb, oproj, g2 + i * 512, be2 + i * 512, x16, nullptr);
        // h1 = relu(x @ W1 + b1) -> bf16
        gemm_bt_k<64, 128, true, true, false, true>
            <<<dim3(16, 16, 1), 256, 0, stream>>>(
            x16, W1T + (size_t)i * 1048576, b1 + i * 2048, h116,
            512, 512, 512, 2048, 0, 0, 0, 1.f);
        // ff partials = h1 @ W2 (split-K 4)
        gemm_bt_k<64, 64, false, false, false, false>
            <<<dim3(8, 16, 4), 256, 0, stream>>>(
            h116, W2T + (size_t)i * 1048576, nullptr, part2,
            512, 2048, 2048, 512, 512, 512, 524288, 1.f);
        ffred_k<<<512, 256, 0, stream>>>(part2, b2 + i * 512, ffb);
        // x = LN(x + ff; g3, beta3), write outs[i]
        ln_k<true><<<1024, 256, 0, stream>>>(xb, ffb, g3 + i * 512, be3 + i * 512, x16,
                                             outs_base + (size_t)i * 524288);
    }
}